// Round 16
// baseline (165.017 us; speedup 1.0000x reference)
//
#include <hip/hip_runtime.h>
#include <hip/hip_bf16.h>
#include <math.h>

typedef short short8 __attribute__((ext_vector_type(8)));
typedef short short4v __attribute__((ext_vector_type(4)));
typedef float f32x4 __attribute__((ext_vector_type(4)));

__device__ __forceinline__ short f2bf(float f) {
  union { float f; unsigned u; } v; v.f = f;
  unsigned r = v.u + 0x7FFFu + ((v.u >> 16) & 1u);
  return (short)(r >> 16);
}
__device__ __forceinline__ float bf2f(short s) {
  union { unsigned u; float f; } v; v.u = ((unsigned)(unsigned short)s) << 16;
  return v.f;
}

// -------- generic f32 -> bf16 cast, 4 elems/thread -----------------------
__global__ __launch_bounds__(256) void cast_kernel(const float* __restrict__ in,
                                                   short* __restrict__ out, int n4) {
  int i = blockIdx.x * blockDim.x + threadIdx.x;
  if (i < n4) {
    float4 v = ((const float4*)in)[i];
    short4v o;
    o.x = f2bf(v.x); o.y = f2bf(v.y); o.z = f2bf(v.z); o.w = f2bf(v.w);
    ((short4v*)out)[i] = o;
  }
}

// -------- DCT even/odd prep: e[n]=x[n]+x[1023-n], o[n]=x[n]-x[1023-n] -----
__global__ __launch_bounds__(256) void prep_eo(const float* __restrict__ x,
                                               short* __restrict__ eo) {
  int t = blockIdx.x * 256 + threadIdx.x;     // 16384 * 128
  int bc = t >> 7, n0 = (t & 127) * 4;        // n0 in [0,512)
  const float* xr = x + (size_t)bc * 1024;
  float4 f = *(const float4*)(xr + n0);
  float4 r = *(const float4*)(xr + 1020 - n0);
  short4v ef, of;
  ef.x = f2bf(f.x + r.w); ef.y = f2bf(f.y + r.z); ef.z = f2bf(f.z + r.y); ef.w = f2bf(f.w + r.x);
  of.x = f2bf(f.x - r.w); of.y = f2bf(f.y - r.z); of.z = f2bf(f.z - r.y); of.w = f2bf(f.w - r.x);
  *(short4v*)&eo[(size_t)bc * 512 + n0] = ef;
  *(short4v*)&eo[8388608 + (size_t)bc * 512 + n0] = of;
}

// -------- Deo[parity][k'][n] = 2*cos(pi/2048 * (2k'+parity) * (2n+1)) -----
__global__ __launch_bounds__(256) void build_Deo(short* __restrict__ D) {
  int t = blockIdx.x * 256 + threadIdx.x;     // 2*512*512 = 524288
  int parity = t >> 18, rem = t & 262143;
  int k2 = rem >> 9, n = rem & 511;
  const float s = 1.5339807878856412e-03f;    // pi/2048
  float arg = (s * (float)(2 * k2 + parity)) * (float)(2 * n + 1);
  D[t] = f2bf(2.0f * cosf(arg));
}

// -------- fold 4 row-block partials -> per-(b,c) mu, rstd -----------------
__global__ __launch_bounds__(256) void ln_stats(const float2* __restrict__ partial,
                                                float2* __restrict__ musd) {
  int n = blockIdx.x * 256 + threadIdx.x;   // 16384
  float S = 0.f, Q = 0.f;
#pragma unroll
  for (int r = 0; r < 4; ++r) {
    float2 p = partial[(size_t)r * 16384 + n];
    S += p.x; Q += p.y;
  }
  float mu  = S * (1.f / 1024.f);
  float var = Q * (1.f / 1024.f) - mu * mu;   // biased, like nn.LayerNorm
  float2 o; o.x = mu; o.y = rsqrtf(var + 1e-6f);
  musd[n] = o;
}

// -------- streaming LN apply: freqT[b][k][c] in place, short8/thread ------
__global__ __launch_bounds__(256) void ln_apply(short* __restrict__ freqT,
                                                const float2* __restrict__ musd,
                                                const float* __restrict__ lnw,
                                                const float* __restrict__ lnb) {
  int t = blockIdx.x * 256 + threadIdx.x;
  int c8 = t & 63;
  int k  = (t >> 6) & 1023;
  int b  = t >> 16;
  size_t idx = ((size_t)b << 19) + (size_t)k * 512 + (size_t)c8 * 8;
  short8 v = *(const short8*)&freqT[idx];
  float w  = lnw[k];
  float bb = lnb[k];
  const float2* ms = &musd[b * 512 + c8 * 8];
  short8 o;
#pragma unroll
  for (int j = 0; j < 8; ++j) {
    float f = bf2f(v[j]);
    float2 m = ms[j];
    o[j] = f2bf((f - m.x) * m.y * w + bb);
  }
  *(short8*)&freqT[idx] = o;
}

// ======== 256x128 BK=32 dbuf BT-GEMM (r13 structure) — used for GEMM1 =====
// Per-wave output 128x64 (acc[8][4]); LDS 48KB -> 2 blocks/CU; counted
// vmcnt(6)/lgkm(6) schedule; swizzle phys slot = logical ^ ((row>>1)&3).
// EPI 0: A=Deo(k'), B=eo; bz=parity; out row=2r+bz; LN partials slot bz*2+bx.
template<int EPI>
__global__ __launch_bounds__(256, 2) void gemmF(
    const short* __restrict__ A, const short* __restrict__ B,
    void* __restrict__ Cout, const float* __restrict__ X,
    float2* __restrict__ P, int K, int NT, long strideA, long strideB)
{
  __shared__ short As[2][8192];    // 256 rows x 32 k
  __shared__ short Bs[2][4096];    // 128 rows x 32 k
  const int tid = threadIdx.x;     // 256
  const int l   = tid & 63;
  const int w   = tid >> 6;        // wave 0..3
  const int wm  = w >> 1;          // 0..1  (M: 128 rows each)
  const int wc  = w & 1;           // 0..1  (N: 64 cols each)
  const int lr  = l & 15;
  const int lhi = l >> 4;

  const int nwg = gridDim.x, q = nwg >> 3, orig = blockIdx.x;
  const int wgid = (orig & 7) * q + (orig >> 3);
  int bx, by, bz;
  bx = wgid & 1; bz = (wgid >> 1) & 1; by = wgid >> 2;

  const long row0 = (long)bx * 256, col0 = (long)by * 128;
  const short* Ab = A + (size_t)bz * strideA + (size_t)row0 * K;
  const short* Bb = B + (size_t)bz * strideB + (size_t)col0 * K;

  const int sx    = (lhi ^ ((lr >> 1) & 3)) * 8;
  const int abase = (wm * 128 + lr) * 32;
  const int bbase = (wc * 64  + lr) * 32;

  f32x4 acc[8][4];
#pragma unroll
  for (int i = 0; i < 8; ++i)
#pragma unroll
    for (int j = 0; j < 4; ++j) acc[i][j] = (f32x4){0.f, 0.f, 0.f, 0.f};

#define GLL(SRC, DST) __builtin_amdgcn_global_load_lds(                      \
      (const __attribute__((address_space(1))) void*)(SRC),                  \
      (__attribute__((address_space(3))) void*)(DST), 16, 0, 0)

#define STAGE(KT, D) do {                                                    \
    const size_t kb_ = (size_t)(KT) * 32;                                    \
    _Pragma("unroll")                                                        \
    for (int r_ = 0; r_ < 4; ++r_) {                                         \
      int c_ = r_ * 256 + tid; int row_ = c_ >> 2; int sl_ = c_ & 3;         \
      int sc_ = (sl_ ^ ((row_ >> 1) & 3)) * 8;                               \
      GLL(Ab + (size_t)row_ * K + kb_ + sc_, &As[D][row_ * 32 + sl_ * 8]);   \
    }                                                                        \
    _Pragma("unroll")                                                        \
    for (int r_ = 0; r_ < 2; ++r_) {                                         \
      int c_ = r_ * 256 + tid; int row_ = c_ >> 2; int sl_ = c_ & 3;         \
      int sc_ = (sl_ ^ ((row_ >> 1) & 3)) * 8;                               \
      GLL(Bb + (size_t)row_ * K + kb_ + sc_, &Bs[D][row_ * 32 + sl_ * 8]);   \
    }                                                                        \
  } while (0)

#define LD8(PTR, OFF) (*(const short8*)&(PTR)[OFF])
#define MFMA(AV, BV, C) __builtin_amdgcn_mfma_f32_16x16x32_bf16(AV, BV, C, 0, 0, 0)
#define SBAR __builtin_amdgcn_s_barrier()
#define SCHB __builtin_amdgcn_sched_barrier(0)

#define MROW(MI, AV)                                                         \
    acc[MI][0] = MFMA(AV, b0, acc[MI][0]);                                   \
    acc[MI][1] = MFMA(AV, b1, acc[MI][1]);                                   \
    acc[MI][2] = MFMA(AV, b2, acc[MI][2]);                                   \
    acc[MI][3] = MFMA(AV, b3, acc[MI][3]);

  STAGE(0, 0);
  STAGE(1, 1);

  int cur = 0;
  for (int kt = 0; kt < NT; ++kt) {
    if (kt + 1 < NT) { asm volatile("s_waitcnt vmcnt(6)" ::: "memory"); }
    else             { asm volatile("s_waitcnt vmcnt(0)" ::: "memory"); }
    SCHB; SBAR;
    const short* Ad = As[cur];
    const short* Bd = Bs[cur];
    short8 a0, a1, a2, a3, a4, a5, a6, a7, b0, b1, b2, b3;
    a0 = LD8(Ad, abase + 0 * 512 + sx);
    a1 = LD8(Ad, abase + 1 * 512 + sx);
    b0 = LD8(Bd, bbase + 0 * 512 + sx);
    b1 = LD8(Bd, bbase + 1 * 512 + sx);
    b2 = LD8(Bd, bbase + 2 * 512 + sx);
    b3 = LD8(Bd, bbase + 3 * 512 + sx);
    a2 = LD8(Ad, abase + 2 * 512 + sx);
    a3 = LD8(Ad, abase + 3 * 512 + sx);
    a4 = LD8(Ad, abase + 4 * 512 + sx);
    a5 = LD8(Ad, abase + 5 * 512 + sx);
    a6 = LD8(Ad, abase + 6 * 512 + sx);
    a7 = LD8(Ad, abase + 7 * 512 + sx);
    SCHB;
    asm volatile("s_waitcnt lgkmcnt(6)" ::: "memory");   // a0,a1,b0-3 ready
    SCHB;
    __builtin_amdgcn_s_setprio(1);
    MROW(0, a0) MROW(1, a1)
    __builtin_amdgcn_s_setprio(0);
    SCHB;
    asm volatile("s_waitcnt lgkmcnt(0)" ::: "memory");   // all reads retired
    SCHB; SBAR;
    if (kt + 2 < NT) STAGE(kt + 2, cur);                 // overlapped by MFMAs
    SCHB;
    __builtin_amdgcn_s_setprio(1);
    MROW(2, a2) MROW(3, a3) MROW(4, a4) MROW(5, a5) MROW(6, a6) MROW(7, a7)
    __builtin_amdgcn_s_setprio(0);
    SCHB;
    cur ^= 1;
  }

  // ---------------- epilogue ----------------
  float sv[4], qv[4];
#pragma unroll
  for (int ni = 0; ni < 4; ++ni) { sv[ni] = 0.f; qv[ni] = 0.f; }

#pragma unroll
  for (int mi = 0; mi < 8; ++mi) {
#pragma unroll
    for (int ni = 0; ni < 4; ++ni) {
#pragma unroll
      for (int j = 0; j < 4; ++j) {
        int r  = (int)row0 + wm * 128 + mi * 16 + lhi * 4 + j;
        int cc = (int)col0 + wc * 64 + ni * 16 + lr;
        float v = acc[mi][ni][j];
        sv[ni] += v; qv[ni] += v * v;
        int rr = r * 2 + bz;     // interleave even/odd k-rows
        ((short*)Cout)[((size_t)(cc >> 9) << 19) + (size_t)rr * 512 + (cc & 511)] = f2bf(v);
      }
    }
  }

  {
    __syncthreads();
    float* redS = (float*)&As[0][0];       // [128 cols][8 contributors]
    float* redQ = redS + 1024;
    const int contrib = wm * 4 + lhi;      // 8 contributors cover 256 rows
#pragma unroll
    for (int ni = 0; ni < 4; ++ni) {
      int ccl = wc * 64 + ni * 16 + lr;
      redS[ccl * 8 + contrib] = sv[ni];
      redQ[ccl * 8 + contrib] = qv[ni];
    }
    __syncthreads();
    if (tid < 128) {
      float S = 0.f, Q = 0.f;
#pragma unroll
      for (int i = 0; i < 8; ++i) { S += redS[tid * 8 + i]; Q += redQ[tid * 8 + i]; }
      float2 o; o.x = S; o.y = Q;
      P[(size_t)(bz * 2 + bx) * 16384 + col0 + tid] = o;
    }
  }
#undef MROW
#undef MFMA
#undef LD8
#undef STAGE
#undef GLL
#undef SBAR
#undef SCHB
}

// ======== 128x128 BK=32 dbuf BT-GEMM, 4 waves, 4 blocks/CU ================
// LDS 32KB (2buf x (128+128)x32x2B); VGPR target <=128 -> 16 waves/CU.
// 4 independent barrier domains per CU: each block's vmcnt/lgkm drains are
// covered by the other 3 blocks' MFMA work (the TLP m97/m114 relied on).
// Per K-tile (=one 16x16x32 k-step): vmcnt(4); bar; 8 ds_read (a0,b0-3,
// a1-3); staggered lgkm(3/2/1/0) between MROWs; bar; STAGE(kt+2,cur).
// Swizzle for 64B rows: phys slot = logical ^ ((row>>1)&3), inverse-permuted
// global source keeps GLL dest linear; ds_read XORs the slot.
// EPI 1: relu -> z1t bf16.  EPI 2: out = x * sigmoid(C), fp32 x.
template<int EPI>
__global__ __launch_bounds__(256, 4) void gemm128(
    const short* __restrict__ A, const short* __restrict__ B,
    void* __restrict__ Cout, const float* __restrict__ X,
    int K, int NT, long strideA, long strideB)
{
  __shared__ short As[2][4096];    // 128 rows x 32 k
  __shared__ short Bs[2][4096];
  const int tid = threadIdx.x;     // 256
  const int l   = tid & 63;
  const int w   = tid >> 6;        // wave 0..3
  const int wm  = w >> 1;          // 0..1
  const int wc  = w & 1;           // 0..1
  const int lr  = l & 15;
  const int lhi = l >> 4;

  const int nwg = gridDim.x, q = nwg >> 3, orig = blockIdx.x;
  const int wgid = (orig & 7) * q + (orig >> 3);
  int bx, by, bz;
  if (EPI == 1) { by = wgid & 7; bx = (wgid >> 3) & 7; bz = wgid >> 6; }
  else          { bx = wgid & 3; by = (wgid >> 2) & 7; bz = wgid >> 5; }

  const long row0 = (long)bx * 128, col0 = (long)by * 128;
  const short* Ab = A + (size_t)bz * strideA + (size_t)row0 * K;
  const short* Bb = B + (size_t)bz * strideB + (size_t)col0 * K;

  // fragment reads: phys slot = lhi ^ ((row>>1)&3), row = ...+lr
  const int sx    = (lhi ^ ((lr >> 1) & 3)) * 8;
  const int abase = (wm * 64 + lr) * 32;
  const int bbase = (wc * 64 + lr) * 32;

  f32x4 acc[4][4];
#pragma unroll
  for (int i = 0; i < 4; ++i)
#pragma unroll
    for (int j = 0; j < 4; ++j) acc[i][j] = (f32x4){0.f, 0.f, 0.f, 0.f};

#define GLL(SRC, DST) __builtin_amdgcn_global_load_lds(                      \
      (const __attribute__((address_space(1))) void*)(SRC),                  \
      (__attribute__((address_space(3))) void*)(DST), 16, 0, 0)

  // staging: chunk c (0..511 per op) -> row c>>2, phys slot c&3 (linear GLL
  // dest); global k-col inverse-swizzled: (c&3) ^ ((row>>1)&3)
#define STAGE(KT, D) do {                                                    \
    const size_t kb_ = (size_t)(KT) * 32;                                    \
    _Pragma("unroll")                                                        \
    for (int r_ = 0; r_ < 2; ++r_) {                                         \
      int c_ = r_ * 256 + tid; int row_ = c_ >> 2; int sl_ = c_ & 3;         \
      int sc_ = (sl_ ^ ((row_ >> 1) & 3)) * 8;                               \
      GLL(Ab + (size_t)row_ * K + kb_ + sc_, &As[D][row_ * 32 + sl_ * 8]);   \
    }                                                                        \
    _Pragma("unroll")                                                        \
    for (int r_ = 0; r_ < 2; ++r_) {                                         \
      int c_ = r_ * 256 + tid; int row_ = c_ >> 2; int sl_ = c_ & 3;         \
      int sc_ = (sl_ ^ ((row_ >> 1) & 3)) * 8;                               \
      GLL(Bb + (size_t)row_ * K + kb_ + sc_, &Bs[D][row_ * 32 + sl_ * 8]);   \
    }                                                                        \
  } while (0)

#define LD8(PTR, OFF) (*(const short8*)&(PTR)[OFF])
#define MFMA(AV, BV, C) __builtin_amdgcn_mfma_f32_16x16x32_bf16(AV, BV, C, 0, 0, 0)
#define SBAR __builtin_amdgcn_s_barrier()
#define SCHB __builtin_amdgcn_sched_barrier(0)

#define MROW(MI, AV)                                                         \
    acc[MI][0] = MFMA(AV, b0, acc[MI][0]);                                   \
    acc[MI][1] = MFMA(AV, b1, acc[MI][1]);                                   \
    acc[MI][2] = MFMA(AV, b2, acc[MI][2]);                                   \
    acc[MI][3] = MFMA(AV, b3, acc[MI][3]);

  STAGE(0, 0);
  STAGE(1, 1);

  int cur = 0;
  for (int kt = 0; kt < NT; ++kt) {
    if (kt + 1 < NT) { asm volatile("s_waitcnt vmcnt(4)" ::: "memory"); }
    else             { asm volatile("s_waitcnt vmcnt(0)" ::: "memory"); }
    SCHB; SBAR;
    const short* Ad = As[cur];
    const short* Bd = Bs[cur];
    short8 a0, a1, a2, a3, b0, b1, b2, b3;
    a0 = LD8(Ad, abase + 0 * 512 + sx);
    b0 = LD8(Bd, bbase + 0 * 512 + sx);
    b1 = LD8(Bd, bbase + 1 * 512 + sx);
    b2 = LD8(Bd, bbase + 2 * 512 + sx);
    b3 = LD8(Bd, bbase + 3 * 512 + sx);
    a1 = LD8(Ad, abase + 1 * 512 + sx);
    a2 = LD8(Ad, abase + 2 * 512 + sx);
    a3 = LD8(Ad, abase + 3 * 512 + sx);
    SCHB;
    asm volatile("s_waitcnt lgkmcnt(3)" ::: "memory");   // a0,b0-3 ready
    SCHB;
    __builtin_amdgcn_s_setprio(1);
    MROW(0, a0)
    __builtin_amdgcn_s_setprio(0);
    SCHB;
    asm volatile("s_waitcnt lgkmcnt(2)" ::: "memory");
    SCHB;
    __builtin_amdgcn_s_setprio(1);
    MROW(1, a1)
    __builtin_amdgcn_s_setprio(0);
    SCHB;
    asm volatile("s_waitcnt lgkmcnt(1)" ::: "memory");
    SCHB;
    __builtin_amdgcn_s_setprio(1);
    MROW(2, a2)
    __builtin_amdgcn_s_setprio(0);
    SCHB;
    asm volatile("s_waitcnt lgkmcnt(0)" ::: "memory");   // all reads retired
    SCHB; SBAR;
    if (kt + 2 < NT) STAGE(kt + 2, cur);                 // overlapped by MROW3
    SCHB;
    __builtin_amdgcn_s_setprio(1);
    MROW(3, a3)
    __builtin_amdgcn_s_setprio(0);
    SCHB;
    cur ^= 1;
  }

  // ---------------- epilogue ----------------
#pragma unroll
  for (int mi = 0; mi < 4; ++mi) {
#pragma unroll
    for (int ni = 0; ni < 4; ++ni) {
#pragma unroll
      for (int j = 0; j < 4; ++j) {
        int r  = (int)row0 + wm * 64 + mi * 16 + lhi * 4 + j;
        int cc = (int)col0 + wc * 64 + ni * 16 + lr;
        float v = acc[mi][ni][j];
        if (EPI == 1) {
          ((short*)Cout)[(size_t)bz * 1048576 + (size_t)r * 1024 + cc] = f2bf(v > 0.f ? v : 0.f);
        } else {
          size_t idx = (size_t)bz * 524288 + (size_t)r * 1024 + cc;
          float g = 1.f / (1.f + __expf(-v));
          ((float*)Cout)[idx] = X[idx] * g;
        }
      }
    }
  }
#undef MROW
#undef MFMA
#undef LD8
#undef STAGE
#undef GLL
#undef SBAR
#undef SCHB
}

extern "C" void kernel_launch(void* const* d_in, const int* in_sizes, int n_in,
                              void* d_out, int out_size, void* d_ws, size_t ws_size,
                              hipStream_t stream) {
  const float* x    = (const float*)d_in[0];   // [32,512,1024]
  const float* w1   = (const float*)d_in[1];   // [1024,512]
  const float* w2   = (const float*)d_in[2];   // [512,1024]
  const float* ln_w = (const float*)d_in[3];   // [1024]
  const float* ln_b = (const float*)d_in[4];   // [1024]
  float* out = (float*)d_out;

  char* ws = (char*)d_ws;
  short* Deo    = (short*)(ws);                  //  1,048,576 B [2][512][512]
  short* w1_bf  = (short*)(ws + 1048576);        //  1,048,576 B
  short* w2_bf  = (short*)(ws + 2097152);        //  1,048,576 B
  short* freqT  = (short*)(ws + 3145728);        // 33,554,432 B [b][k][c]
  short* z1t    = (short*)(ws + 36700160);       // 67,108,864 B [b][p][o]
  short* eo     = z1t;                           // e/o alias z1t (dead by GEMM2)
  float2* part  = (float2*)(ws + 103809024);     //    524,288 B [4][16384]
  float2* musd  = (float2*)(ws + 104857600);     //    131,072 B [16384]
  // total ~105 MB

  prep_eo<<<dim3(8192), dim3(256), 0, stream>>>(x, eo);
  cast_kernel<<<dim3(512), dim3(256), 0, stream>>>(w1, w1_bf, 524288 / 4);
  cast_kernel<<<dim3(512), dim3(256), 0, stream>>>(w2, w2_bf, 524288 / 4);
  build_Deo<<<dim3(2048), dim3(256), 0, stream>>>(Deo);

  // GEMM1 (even/odd): C[k',(b,c)] = sum_n Deo[p][k',n]*eo[p][(b,c),n]
  // -> freqT rows 2k'+p, + LN partials. K=512, NT=16, grid 2bx*2p*128by.
  gemmF<0><<<dim3(512), dim3(256), 0, stream>>>(
      Deo, eo, (void*)freqT, nullptr, part, 512, 16, 262144, 8388608);

  // LN stats: fold 4 partials (2 parity x 2 bx) -> (mu, rstd) per (b,c)
  ln_stats<<<dim3(64), dim3(256), 0, stream>>>(part, musd);

  // LN apply: normalize freqT in place (streaming, vectorized)
  ln_apply<<<dim3(8192), dim3(256), 0, stream>>>(freqT, musd, ln_w, ln_b);

  // GEMM2: C[p,o] = sum_c Ht[b][p,c] * w1[o,c], relu -> z1t[b][p][o]
  gemm128<1><<<dim3(2048), dim3(256), 0, stream>>>(
      freqT, w1_bf, (void*)z1t, nullptr, 512, 16, 524288, 0);

  // GEMM3: C[o2,p] = sum_j w2[o2,j] * z1t[b][p,j]; out = x * sigmoid(C)
  gemm128<2><<<dim3(1024), dim3(256), 0, stream>>>(
      w2_bf, z1t, (void*)out, x, 1024, 32, 0, 1048576);
}

// Round 17
// 159.850 us; speedup vs baseline: 1.0323x; 1.0323x over previous
//
#include <hip/hip_runtime.h>
#include <hip/hip_bf16.h>
#include <math.h>

typedef short short8 __attribute__((ext_vector_type(8)));
typedef short short4v __attribute__((ext_vector_type(4)));
typedef float f32x4 __attribute__((ext_vector_type(4)));

__device__ __forceinline__ short f2bf(float f) {
  union { float f; unsigned u; } v; v.f = f;
  unsigned r = v.u + 0x7FFFu + ((v.u >> 16) & 1u);
  return (short)(r >> 16);
}
__device__ __forceinline__ float bf2f(short s) {
  union { unsigned u; float f; } v; v.u = ((unsigned)(unsigned short)s) << 16;
  return v.f;
}

// -------- fused weight cast: w1 (524288) then w2 (524288), 4 elems/thread -
__global__ __launch_bounds__(256) void cast_w(const float* __restrict__ w1,
                                              const float* __restrict__ w2,
                                              short* __restrict__ w1_bf,
                                              short* __restrict__ w2_bf) {
  int i = blockIdx.x * blockDim.x + threadIdx.x;   // 262144 total (x4 elems)
  const float* src = (i < 131072) ? w1 : w2;
  short* dst = (i < 131072) ? w1_bf : w2_bf;
  int j = (i < 131072) ? i : i - 131072;
  float4 v = ((const float4*)src)[j];
  short4v o;
  o.x = f2bf(v.x); o.y = f2bf(v.y); o.z = f2bf(v.z); o.w = f2bf(v.w);
  ((short4v*)dst)[j] = o;
}

// -------- DCT even/odd prep: e[n]=x[n]+x[1023-n], o[n]=x[n]-x[1023-n] -----
__global__ __launch_bounds__(256) void prep_eo(const float* __restrict__ x,
                                               short* __restrict__ eo) {
  int t = blockIdx.x * 256 + threadIdx.x;     // 16384 * 128
  int bc = t >> 7, n0 = (t & 127) * 4;        // n0 in [0,512)
  const float* xr = x + (size_t)bc * 1024;
  float4 f = *(const float4*)(xr + n0);
  float4 r = *(const float4*)(xr + 1020 - n0);
  short4v ef, of;
  ef.x = f2bf(f.x + r.w); ef.y = f2bf(f.y + r.z); ef.z = f2bf(f.z + r.y); ef.w = f2bf(f.w + r.x);
  of.x = f2bf(f.x - r.w); of.y = f2bf(f.y - r.z); of.z = f2bf(f.z - r.y); of.w = f2bf(f.w - r.x);
  *(short4v*)&eo[(size_t)bc * 512 + n0] = ef;
  *(short4v*)&eo[8388608 + (size_t)bc * 512 + n0] = of;
}

// -------- Deo[parity][k'][n] = 2*cos(pi/2048 * (2k'+parity) * (2n+1)) -----
__global__ __launch_bounds__(256) void build_Deo(short* __restrict__ D) {
  int t = blockIdx.x * 256 + threadIdx.x;     // 2*512*512 = 524288
  int parity = t >> 18, rem = t & 262143;
  int k2 = rem >> 9, n = rem & 511;
  const float s = 1.5339807878856412e-03f;    // pi/2048
  float arg = (s * (float)(2 * k2 + parity)) * (float)(2 * n + 1);
  D[t] = f2bf(2.0f * cosf(arg));
}

// -------- fold 4 row-block partials -> per-(b,c) mu, rstd -----------------
__global__ __launch_bounds__(256) void ln_stats(const float2* __restrict__ partial,
                                                float2* __restrict__ musd) {
  int n = blockIdx.x * 256 + threadIdx.x;   // 16384
  float S = 0.f, Q = 0.f;
#pragma unroll
  for (int r = 0; r < 4; ++r) {
    float2 p = partial[(size_t)r * 16384 + n];
    S += p.x; Q += p.y;
  }
  float mu  = S * (1.f / 1024.f);
  float var = Q * (1.f / 1024.f) - mu * mu;   // biased, like nn.LayerNorm
  float2 o; o.x = mu; o.y = rsqrtf(var + 1e-6f);
  musd[n] = o;
}

// -------- streaming LN apply: freqT[b][k][c] in place, short8/thread ------
__global__ __launch_bounds__(256) void ln_apply(short* __restrict__ freqT,
                                                const float2* __restrict__ musd,
                                                const float* __restrict__ lnw,
                                                const float* __restrict__ lnb) {
  int t = blockIdx.x * 256 + threadIdx.x;
  int c8 = t & 63;
  int k  = (t >> 6) & 1023;
  int b  = t >> 16;
  size_t idx = ((size_t)b << 19) + (size_t)k * 512 + (size_t)c8 * 8;
  short8 v = *(const short8*)&freqT[idx];
  float w  = lnw[k];
  float bb = lnb[k];
  const float2* ms = &musd[b * 512 + c8 * 8];
  short8 o;
#pragma unroll
  for (int j = 0; j < 8; ++j) {
    float f = bf2f(v[j]);
    float2 m = ms[j];
    o[j] = f2bf((f - m.x) * m.y * w + bb);
  }
  *(short8*)&freqT[idx] = o;
}

// ======== 256x128 BK=32 dbuf BT-GEMM (r13 structure) — used for GEMM1 =====
// Per-wave output 128x64 (acc[8][4]); LDS 48KB -> 2 blocks/CU; counted
// vmcnt(6)/lgkm(6) schedule; swizzle phys slot = logical ^ ((row>>1)&3).
// EPI 0: A=Deo(k'), B=eo; bz=parity; out row=2r+bz; LN partials slot bz*2+bx.
template<int EPI>
__global__ __launch_bounds__(256, 2) void gemmF(
    const short* __restrict__ A, const short* __restrict__ B,
    void* __restrict__ Cout, const float* __restrict__ X,
    float2* __restrict__ P, int K, int NT, long strideA, long strideB)
{
  __shared__ short As[2][8192];    // 256 rows x 32 k
  __shared__ short Bs[2][4096];    // 128 rows x 32 k
  const int tid = threadIdx.x;     // 256
  const int l   = tid & 63;
  const int w   = tid >> 6;        // wave 0..3
  const int wm  = w >> 1;          // 0..1  (M: 128 rows each)
  const int wc  = w & 1;           // 0..1  (N: 64 cols each)
  const int lr  = l & 15;
  const int lhi = l >> 4;

  const int nwg = gridDim.x, q = nwg >> 3, orig = blockIdx.x;
  const int wgid = (orig & 7) * q + (orig >> 3);
  int bx, by, bz;
  bx = wgid & 1; bz = (wgid >> 1) & 1; by = wgid >> 2;

  const long row0 = (long)bx * 256, col0 = (long)by * 128;
  const short* Ab = A + (size_t)bz * strideA + (size_t)row0 * K;
  const short* Bb = B + (size_t)bz * strideB + (size_t)col0 * K;

  const int sx    = (lhi ^ ((lr >> 1) & 3)) * 8;
  const int abase = (wm * 128 + lr) * 32;
  const int bbase = (wc * 64  + lr) * 32;

  f32x4 acc[8][4];
#pragma unroll
  for (int i = 0; i < 8; ++i)
#pragma unroll
    for (int j = 0; j < 4; ++j) acc[i][j] = (f32x4){0.f, 0.f, 0.f, 0.f};

#define GLL(SRC, DST) __builtin_amdgcn_global_load_lds(                      \
      (const __attribute__((address_space(1))) void*)(SRC),                  \
      (__attribute__((address_space(3))) void*)(DST), 16, 0, 0)

#define STAGE(KT, D) do {                                                    \
    const size_t kb_ = (size_t)(KT) * 32;                                    \
    _Pragma("unroll")                                                        \
    for (int r_ = 0; r_ < 4; ++r_) {                                         \
      int c_ = r_ * 256 + tid; int row_ = c_ >> 2; int sl_ = c_ & 3;         \
      int sc_ = (sl_ ^ ((row_ >> 1) & 3)) * 8;                               \
      GLL(Ab + (size_t)row_ * K + kb_ + sc_, &As[D][row_ * 32 + sl_ * 8]);   \
    }                                                                        \
    _Pragma("unroll")                                                        \
    for (int r_ = 0; r_ < 2; ++r_) {                                         \
      int c_ = r_ * 256 + tid; int row_ = c_ >> 2; int sl_ = c_ & 3;         \
      int sc_ = (sl_ ^ ((row_ >> 1) & 3)) * 8;                               \
      GLL(Bb + (size_t)row_ * K + kb_ + sc_, &Bs[D][row_ * 32 + sl_ * 8]);   \
    }                                                                        \
  } while (0)

#define LD8(PTR, OFF) (*(const short8*)&(PTR)[OFF])
#define MFMA(AV, BV, C) __builtin_amdgcn_mfma_f32_16x16x32_bf16(AV, BV, C, 0, 0, 0)
#define SBAR __builtin_amdgcn_s_barrier()
#define SCHB __builtin_amdgcn_sched_barrier(0)

#define MROW(MI, AV)                                                         \
    acc[MI][0] = MFMA(AV, b0, acc[MI][0]);                                   \
    acc[MI][1] = MFMA(AV, b1, acc[MI][1]);                                   \
    acc[MI][2] = MFMA(AV, b2, acc[MI][2]);                                   \
    acc[MI][3] = MFMA(AV, b3, acc[MI][3]);

  STAGE(0, 0);
  STAGE(1, 1);

  int cur = 0;
  for (int kt = 0; kt < NT; ++kt) {
    if (kt + 1 < NT) { asm volatile("s_waitcnt vmcnt(6)" ::: "memory"); }
    else             { asm volatile("s_waitcnt vmcnt(0)" ::: "memory"); }
    SCHB; SBAR;
    const short* Ad = As[cur];
    const short* Bd = Bs[cur];
    short8 a0, a1, a2, a3, a4, a5, a6, a7, b0, b1, b2, b3;
    a0 = LD8(Ad, abase + 0 * 512 + sx);
    a1 = LD8(Ad, abase + 1 * 512 + sx);
    b0 = LD8(Bd, bbase + 0 * 512 + sx);
    b1 = LD8(Bd, bbase + 1 * 512 + sx);
    b2 = LD8(Bd, bbase + 2 * 512 + sx);
    b3 = LD8(Bd, bbase + 3 * 512 + sx);
    a2 = LD8(Ad, abase + 2 * 512 + sx);
    a3 = LD8(Ad, abase + 3 * 512 + sx);
    a4 = LD8(Ad, abase + 4 * 512 + sx);
    a5 = LD8(Ad, abase + 5 * 512 + sx);
    a6 = LD8(Ad, abase + 6 * 512 + sx);
    a7 = LD8(Ad, abase + 7 * 512 + sx);
    SCHB;
    asm volatile("s_waitcnt lgkmcnt(6)" ::: "memory");   // a0,a1,b0-3 ready
    SCHB;
    __builtin_amdgcn_s_setprio(1);
    MROW(0, a0) MROW(1, a1)
    __builtin_amdgcn_s_setprio(0);
    SCHB;
    asm volatile("s_waitcnt lgkmcnt(0)" ::: "memory");   // all reads retired
    SCHB; SBAR;
    if (kt + 2 < NT) STAGE(kt + 2, cur);                 // overlapped by MFMAs
    SCHB;
    __builtin_amdgcn_s_setprio(1);
    MROW(2, a2) MROW(3, a3) MROW(4, a4) MROW(5, a5) MROW(6, a6) MROW(7, a7)
    __builtin_amdgcn_s_setprio(0);
    SCHB;
    cur ^= 1;
  }

  // ---------------- epilogue ----------------
  float sv[4], qv[4];
#pragma unroll
  for (int ni = 0; ni < 4; ++ni) { sv[ni] = 0.f; qv[ni] = 0.f; }

#pragma unroll
  for (int mi = 0; mi < 8; ++mi) {
#pragma unroll
    for (int ni = 0; ni < 4; ++ni) {
#pragma unroll
      for (int j = 0; j < 4; ++j) {
        int r  = (int)row0 + wm * 128 + mi * 16 + lhi * 4 + j;
        int cc = (int)col0 + wc * 64 + ni * 16 + lr;
        float v = acc[mi][ni][j];
        sv[ni] += v; qv[ni] += v * v;
        int rr = r * 2 + bz;     // interleave even/odd k-rows
        ((short*)Cout)[((size_t)(cc >> 9) << 19) + (size_t)rr * 512 + (cc & 511)] = f2bf(v);
      }
    }
  }

  {
    __syncthreads();
    float* redS = (float*)&As[0][0];       // [128 cols][8 contributors]
    float* redQ = redS + 1024;
    const int contrib = wm * 4 + lhi;      // 8 contributors cover 256 rows
#pragma unroll
    for (int ni = 0; ni < 4; ++ni) {
      int ccl = wc * 64 + ni * 16 + lr;
      redS[ccl * 8 + contrib] = sv[ni];
      redQ[ccl * 8 + contrib] = qv[ni];
    }
    __syncthreads();
    if (tid < 128) {
      float S = 0.f, Q = 0.f;
#pragma unroll
      for (int i = 0; i < 8; ++i) { S += redS[tid * 8 + i]; Q += redQ[tid * 8 + i]; }
      float2 o; o.x = S; o.y = Q;
      P[(size_t)(bz * 2 + bx) * 16384 + col0 + tid] = o;
    }
  }
#undef MROW
#undef MFMA
#undef LD8
#undef STAGE
#undef GLL
#undef SBAR
#undef SCHB
}

// ======== 128x128 dbuf BT-GEMM, 4 waves, 2 blocks/CU (r9 structure) =======
// Deep block queues (2048/1024 grids) — best measured for GEMM2/GEMM3.
// EPI 1: relu -> z1t bf16.  EPI 2: out = x * sigmoid(C), fp32 x.
template<int EPI>
__global__ __launch_bounds__(256, 2) void gemm128(
    const short* __restrict__ A, const short* __restrict__ B,
    void* __restrict__ Cout, const float* __restrict__ X,
    int K, int NT, long strideA, long strideB)
{
  __shared__ short As[2][8192];
  __shared__ short Bs[2][8192];
  const int tid = threadIdx.x;     // 256
  const int l   = tid & 63;
  const int w   = tid >> 6;        // wave 0..3
  const int wm  = w >> 1;          // 0..1
  const int wc  = w & 1;           // 0..1
  const int l7  = l & 7;
  const int lr  = l & 15;
  const int lhi = l >> 4;

  const int nwg = gridDim.x, q = nwg >> 3, orig = blockIdx.x;
  const int wgid = (orig & 7) * q + (orig >> 3);
  int bx, by, bz;
  if (EPI == 1) { by = wgid & 7; bx = (wgid >> 3) & 7; bz = wgid >> 6; }
  else          { bx = wgid & 3; by = (wgid >> 2) & 7; bz = wgid >> 5; }

  const long row0 = (long)bx * 128, col0 = (long)by * 128;
  const short* Ab = A + (size_t)bz * strideA + (size_t)row0 * K;
  const short* Bb = B + (size_t)bz * strideB + (size_t)col0 * K;

  const int rowb  = tid >> 3;                       // 0..31
  const int colel = ((tid & 7) ^ ((tid >> 3) & 7)) * 8;
  const int abase = (wm * 64 + lr) * 64;
  const int bbase = (wc * 64 + lr) * 64;
  const int s0 = ((lhi    ) ^ l7) * 8;
  const int s1 = ((lhi + 4) ^ l7) * 8;

  f32x4 acc[4][4];
#pragma unroll
  for (int i = 0; i < 4; ++i)
#pragma unroll
    for (int j = 0; j < 4; ++j) acc[i][j] = (f32x4){0.f, 0.f, 0.f, 0.f};

#define GLL(SRC, DST) __builtin_amdgcn_global_load_lds(                      \
      (const __attribute__((address_space(1))) void*)(SRC),                  \
      (__attribute__((address_space(3))) void*)(DST), 16, 0, 0)

#define STAGE(KT, D) do {                                                    \
    const size_t ko_ = (size_t)(KT) * 64 + colel;                            \
    _Pragma("unroll")                                                        \
    for (int r_ = 0; r_ < 4; ++r_)                                           \
      GLL(Ab + (size_t)(r_ * 32 + rowb) * K + ko_,                           \
          &As[D][(r_ * 32 + rowb) * 64 + (tid & 7) * 8]);                    \
    _Pragma("unroll")                                                        \
    for (int r_ = 0; r_ < 4; ++r_)                                           \
      GLL(Bb + (size_t)(r_ * 32 + rowb) * K + ko_,                           \
          &Bs[D][(r_ * 32 + rowb) * 64 + (tid & 7) * 8]);                    \
  } while (0)

#define LD8(PTR, OFF) (*(const short8*)&(PTR)[OFF])
#define MFMA(AV, BV, C) __builtin_amdgcn_mfma_f32_16x16x32_bf16(AV, BV, C, 0, 0, 0)
#define SBAR __builtin_amdgcn_s_barrier()
#define SCHB __builtin_amdgcn_sched_barrier(0)

#define MFMA16(A0, A1, A2, A3, B0, B1, B2, B3)                               \
    __builtin_amdgcn_s_setprio(1);                                           \
    acc[0][0]=MFMA(A0,B0,acc[0][0]); acc[0][1]=MFMA(A0,B1,acc[0][1]);        \
    acc[0][2]=MFMA(A0,B2,acc[0][2]); acc[0][3]=MFMA(A0,B3,acc[0][3]);        \
    acc[1][0]=MFMA(A1,B0,acc[1][0]); acc[1][1]=MFMA(A1,B1,acc[1][1]);        \
    acc[1][2]=MFMA(A1,B2,acc[1][2]); acc[1][3]=MFMA(A1,B3,acc[1][3]);        \
    acc[2][0]=MFMA(A2,B0,acc[2][0]); acc[2][1]=MFMA(A2,B1,acc[2][1]);        \
    acc[2][2]=MFMA(A2,B2,acc[2][2]); acc[2][3]=MFMA(A2,B3,acc[2][3]);        \
    acc[3][0]=MFMA(A3,B0,acc[3][0]); acc[3][1]=MFMA(A3,B1,acc[3][1]);        \
    acc[3][2]=MFMA(A3,B2,acc[3][2]); acc[3][3]=MFMA(A3,B3,acc[3][3]);        \
    __builtin_amdgcn_s_setprio(0);

  STAGE(0, 0);
  STAGE(1, 1);

  int cur = 0;
  for (int kt = 0; kt < NT; ++kt) {
    if (kt + 1 < NT) { asm volatile("s_waitcnt vmcnt(8)" ::: "memory"); }
    else             { asm volatile("s_waitcnt vmcnt(0)" ::: "memory"); }
    SCHB; SBAR;
    const short* Ad = As[cur];
    const short* Bd = Bs[cur];
    short8 a00, a01, a02, a03, b00, b01, b02, b03;
    short8 a10, a11, a12, a13, b10, b11, b12, b13;
    a00 = LD8(Ad, abase + 0 * 1024 + s0);
    a01 = LD8(Ad, abase + 1 * 1024 + s0);
    a02 = LD8(Ad, abase + 2 * 1024 + s0);
    a03 = LD8(Ad, abase + 3 * 1024 + s0);
    b00 = LD8(Bd, bbase + 0 * 1024 + s0);
    b01 = LD8(Bd, bbase + 1 * 1024 + s0);
    b02 = LD8(Bd, bbase + 2 * 1024 + s0);
    b03 = LD8(Bd, bbase + 3 * 1024 + s0);
    a10 = LD8(Ad, abase + 0 * 1024 + s1);
    a11 = LD8(Ad, abase + 1 * 1024 + s1);
    a12 = LD8(Ad, abase + 2 * 1024 + s1);
    a13 = LD8(Ad, abase + 3 * 1024 + s1);
    b10 = LD8(Bd, bbase + 0 * 1024 + s1);
    b11 = LD8(Bd, bbase + 1 * 1024 + s1);
    b12 = LD8(Bd, bbase + 2 * 1024 + s1);
    b13 = LD8(Bd, bbase + 3 * 1024 + s1);
    SCHB;
    asm volatile("s_waitcnt lgkmcnt(8)" ::: "memory");
    SCHB;
    MFMA16(a00, a01, a02, a03, b00, b01, b02, b03)
    SCHB;
    asm volatile("s_waitcnt lgkmcnt(0)" ::: "memory");
    SCHB; SBAR;
    if (kt + 2 < NT) STAGE(kt + 2, cur);
    SCHB;
    MFMA16(a10, a11, a12, a13, b10, b11, b12, b13)
    SCHB;
    cur ^= 1;
  }

  // ---------------- epilogue ----------------
#pragma unroll
  for (int mi = 0; mi < 4; ++mi) {
#pragma unroll
    for (int ni = 0; ni < 4; ++ni) {
#pragma unroll
      for (int j = 0; j < 4; ++j) {
        int r  = (int)row0 + wm * 64 + mi * 16 + lhi * 4 + j;
        int cc = (int)col0 + wc * 64 + ni * 16 + lr;
        float v = acc[mi][ni][j];
        if (EPI == 1) {
          ((short*)Cout)[(size_t)bz * 1048576 + (size_t)r * 1024 + cc] = f2bf(v > 0.f ? v : 0.f);
        } else {
          size_t idx = (size_t)bz * 524288 + (size_t)r * 1024 + cc;
          float g = 1.f / (1.f + __expf(-v));
          ((float*)Cout)[idx] = X[idx] * g;
        }
      }
    }
  }
#undef MFMA16
#undef MFMA
#undef LD8
#undef STAGE
#undef GLL
#undef SBAR
#undef SCHB
}

extern "C" void kernel_launch(void* const* d_in, const int* in_sizes, int n_in,
                              void* d_out, int out_size, void* d_ws, size_t ws_size,
                              hipStream_t stream) {
  const float* x    = (const float*)d_in[0];   // [32,512,1024]
  const float* w1   = (const float*)d_in[1];   // [1024,512]
  const float* w2   = (const float*)d_in[2];   // [512,1024]
  const float* ln_w = (const float*)d_in[3];   // [1024]
  const float* ln_b = (const float*)d_in[4];   // [1024]
  float* out = (float*)d_out;

  char* ws = (char*)d_ws;
  short* Deo    = (short*)(ws);                  //  1,048,576 B [2][512][512]
  short* w1_bf  = (short*)(ws + 1048576);        //  1,048,576 B
  short* w2_bf  = (short*)(ws + 2097152);        //  1,048,576 B
  short* freqT  = (short*)(ws + 3145728);        // 33,554,432 B [b][k][c]
  short* z1t    = (short*)(ws + 36700160);       // 67,108,864 B [b][p][o]
  short* eo     = z1t;                           // e/o alias z1t (dead by GEMM2)
  float2* part  = (float2*)(ws + 103809024);     //    524,288 B [4][16384]
  float2* musd  = (float2*)(ws + 104857600);     //    131,072 B [16384]
  // total ~105 MB

  prep_eo<<<dim3(8192), dim3(256), 0, stream>>>(x, eo);
  cast_w<<<dim3(1024), dim3(256), 0, stream>>>(w1, w2, w1_bf, w2_bf);
  build_Deo<<<dim3(2048), dim3(256), 0, stream>>>(Deo);

  // GEMM1 (even/odd): C[k',(b,c)] = sum_n Deo[p][k',n]*eo[p][(b,c),n]
  // -> freqT rows 2k'+p, + LN partials. K=512, NT=16, grid 2bx*2p*128by.
  gemmF<0><<<dim3(512), dim3(256), 0, stream>>>(
      Deo, eo, (void*)freqT, nullptr, part, 512, 16, 262144, 8388608);

  // LN stats: fold 4 partials (2 parity x 2 bx) -> (mu, rstd) per (b,c)
  ln_stats<<<dim3(64), dim3(256), 0, stream>>>(part, musd);

  // LN apply: normalize freqT in place (streaming, vectorized)
  ln_apply<<<dim3(8192), dim3(256), 0, stream>>>(freqT, musd, ln_w, ln_b);

  // GEMM2: C[p,o] = sum_c Ht[b][p,c] * w1[o,c], relu -> z1t[b][p][o]
  gemm128<1><<<dim3(2048), dim3(256), 0, stream>>>(
      freqT, w1_bf, (void*)z1t, nullptr, 512, 8, 524288, 0);

  // GEMM3: C[o2,p] = sum_j w2[o2,j] * z1t[b][p,j]; out = x * sigmoid(C)
  gemm128<2><<<dim3(1024), dim3(256), 0, stream>>>(
      w2_bf, z1t, (void*)out, x, 1024, 16, 0, 1048576);
}

// Round 18
// 159.625 us; speedup vs baseline: 1.0338x; 1.0014x over previous
//
#include <hip/hip_runtime.h>
#include <hip/hip_bf16.h>
#include <math.h>

typedef short short8 __attribute__((ext_vector_type(8)));
typedef short short4v __attribute__((ext_vector_type(4)));
typedef float f32x4 __attribute__((ext_vector_type(4)));

__device__ __forceinline__ short f2bf(float f) {
  union { float f; unsigned u; } v; v.f = f;
  unsigned r = v.u + 0x7FFFu + ((v.u >> 16) & 1u);
  return (short)(r >> 16);
}
__device__ __forceinline__ float bf2f(short s) {
  union { unsigned u; float f; } v; v.u = ((unsigned)(unsigned short)s) << 16;
  return v.f;
}

// -------- fused weight cast: w1 then w2, 4 elems/thread -------------------
__global__ __launch_bounds__(256) void cast_w(const float* __restrict__ w1,
                                              const float* __restrict__ w2,
                                              short* __restrict__ w1_bf,
                                              short* __restrict__ w2_bf) {
  int i = blockIdx.x * blockDim.x + threadIdx.x;   // 262144 total (x4 elems)
  const float* src = (i < 131072) ? w1 : w2;
  short* dst = (i < 131072) ? w1_bf : w2_bf;
  int j = (i < 131072) ? i : i - 131072;
  float4 v = ((const float4*)src)[j];
  short4v o;
  o.x = f2bf(v.x); o.y = f2bf(v.y); o.z = f2bf(v.z); o.w = f2bf(v.w);
  ((short4v*)dst)[j] = o;
}

// -------- DCT even/odd prep: e[n]=x[n]+x[1023-n], o[n]=x[n]-x[1023-n] -----
__global__ __launch_bounds__(256) void prep_eo(const float* __restrict__ x,
                                               short* __restrict__ eo) {
  int t = blockIdx.x * 256 + threadIdx.x;     // 16384 * 128
  int bc = t >> 7, n0 = (t & 127) * 4;        // n0 in [0,512)
  const float* xr = x + (size_t)bc * 1024;
  float4 f = *(const float4*)(xr + n0);
  float4 r = *(const float4*)(xr + 1020 - n0);
  short4v ef, of;
  ef.x = f2bf(f.x + r.w); ef.y = f2bf(f.y + r.z); ef.z = f2bf(f.z + r.y); ef.w = f2bf(f.w + r.x);
  of.x = f2bf(f.x - r.w); of.y = f2bf(f.y - r.z); of.z = f2bf(f.z - r.y); of.w = f2bf(f.w - r.x);
  *(short4v*)&eo[(size_t)bc * 512 + n0] = ef;
  *(short4v*)&eo[8388608 + (size_t)bc * 512 + n0] = of;
}

// -------- Deo[parity][k'][n] = 2*cos(pi/2048 * (2k'+parity) * (2n+1)) -----
__global__ __launch_bounds__(256) void build_Deo(short* __restrict__ D) {
  int t = blockIdx.x * 256 + threadIdx.x;     // 2*512*512 = 524288
  int parity = t >> 18, rem = t & 262143;
  int k2 = rem >> 9, n = rem & 511;
  const float s = 1.5339807878856412e-03f;    // pi/2048
  float arg = (s * (float)(2 * k2 + parity)) * (float)(2 * n + 1);
  D[t] = f2bf(2.0f * cosf(arg));
}

// -------- fold 4 row-block partials -> per-(b,c) mu, rstd -----------------
__global__ __launch_bounds__(256) void ln_stats(const float2* __restrict__ partial,
                                                float2* __restrict__ musd) {
  int n = blockIdx.x * 256 + threadIdx.x;   // 16384
  float S = 0.f, Q = 0.f;
#pragma unroll
  for (int r = 0; r < 4; ++r) {
    float2 p = partial[(size_t)r * 16384 + n];
    S += p.x; Q += p.y;
  }
  float mu  = S * (1.f / 1024.f);
  float var = Q * (1.f / 1024.f) - mu * mu;   // biased, like nn.LayerNorm
  float2 o; o.x = mu; o.y = rsqrtf(var + 1e-6f);
  musd[n] = o;
}

// -------- streaming LN apply: freqT[b][k][c] in place, short8/thread ------
__global__ __launch_bounds__(256) void ln_apply(short* __restrict__ freqT,
                                                const float2* __restrict__ musd,
                                                const float* __restrict__ lnw,
                                                const float* __restrict__ lnb) {
  int t = blockIdx.x * 256 + threadIdx.x;
  int c8 = t & 63;
  int k  = (t >> 6) & 1023;
  int b  = t >> 16;
  size_t idx = ((size_t)b << 19) + (size_t)k * 512 + (size_t)c8 * 8;
  short8 v = *(const short8*)&freqT[idx];
  float w  = lnw[k];
  float bb = lnb[k];
  const float2* ms = &musd[b * 512 + c8 * 8];
  short8 o;
#pragma unroll
  for (int j = 0; j < 8; ++j) {
    float f = bf2f(v[j]);
    float2 m = ms[j];
    o[j] = f2bf((f - m.x) * m.y * w + bb);
  }
  *(short8*)&freqT[idx] = o;
}

// ======== 256x128 BK=32 dbuf BT-GEMM (r13 structure) — GEMM1 ==============
// Per-wave output 128x64 (acc[8][4]); LDS 48KB -> 2 blocks/CU; counted
// vmcnt(6)/lgkm(6) schedule; swizzle phys slot = logical ^ ((row>>1)&3).
// A=Deo(k'), B=eo; bz=parity; out row=2r+bz; LN partials slot bz*2+bx.
__global__ __launch_bounds__(256, 2) void gemm1F(
    const short* __restrict__ A, const short* __restrict__ B,
    void* __restrict__ Cout, float2* __restrict__ P,
    int K, int NT, long strideA, long strideB)
{
  __shared__ short As[2][8192];    // 256 rows x 32 k
  __shared__ short Bs[2][4096];    // 128 rows x 32 k
  const int tid = threadIdx.x;     // 256
  const int l   = tid & 63;
  const int w   = tid >> 6;        // wave 0..3
  const int wm  = w >> 1;
  const int wc  = w & 1;
  const int lr  = l & 15;
  const int lhi = l >> 4;

  const int nwg = gridDim.x, q = nwg >> 3, orig = blockIdx.x;
  const int wgid = (orig & 7) * q + (orig >> 3);
  int bx = wgid & 1, bz = (wgid >> 1) & 1, by = wgid >> 2;

  const long row0 = (long)bx * 256, col0 = (long)by * 128;
  const short* Ab = A + (size_t)bz * strideA + (size_t)row0 * K;
  const short* Bb = B + (size_t)bz * strideB + (size_t)col0 * K;

  const int sx    = (lhi ^ ((lr >> 1) & 3)) * 8;
  const int abase = (wm * 128 + lr) * 32;
  const int bbase = (wc * 64  + lr) * 32;

  f32x4 acc[8][4];
#pragma unroll
  for (int i = 0; i < 8; ++i)
#pragma unroll
    for (int j = 0; j < 4; ++j) acc[i][j] = (f32x4){0.f, 0.f, 0.f, 0.f};

#define GLL(SRC, DST) __builtin_amdgcn_global_load_lds(                      \
      (const __attribute__((address_space(1))) void*)(SRC),                  \
      (__attribute__((address_space(3))) void*)(DST), 16, 0, 0)

#define STAGE(KT, D) do {                                                    \
    const size_t kb_ = (size_t)(KT) * 32;                                    \
    _Pragma("unroll")                                                        \
    for (int r_ = 0; r_ < 4; ++r_) {                                         \
      int c_ = r_ * 256 + tid; int row_ = c_ >> 2; int sl_ = c_ & 3;         \
      int sc_ = (sl_ ^ ((row_ >> 1) & 3)) * 8;                               \
      GLL(Ab + (size_t)row_ * K + kb_ + sc_, &As[D][row_ * 32 + sl_ * 8]);   \
    }                                                                        \
    _Pragma("unroll")                                                        \
    for (int r_ = 0; r_ < 2; ++r_) {                                         \
      int c_ = r_ * 256 + tid; int row_ = c_ >> 2; int sl_ = c_ & 3;         \
      int sc_ = (sl_ ^ ((row_ >> 1) & 3)) * 8;                               \
      GLL(Bb + (size_t)row_ * K + kb_ + sc_, &Bs[D][row_ * 32 + sl_ * 8]);   \
    }                                                                        \
  } while (0)

#define LD8(PTR, OFF) (*(const short8*)&(PTR)[OFF])
#define MFMA(AV, BV, C) __builtin_amdgcn_mfma_f32_16x16x32_bf16(AV, BV, C, 0, 0, 0)
#define SBAR __builtin_amdgcn_s_barrier()
#define SCHB __builtin_amdgcn_sched_barrier(0)

#define MROW(MI, AV)                                                         \
    acc[MI][0] = MFMA(AV, b0, acc[MI][0]);                                   \
    acc[MI][1] = MFMA(AV, b1, acc[MI][1]);                                   \
    acc[MI][2] = MFMA(AV, b2, acc[MI][2]);                                   \
    acc[MI][3] = MFMA(AV, b3, acc[MI][3]);

  STAGE(0, 0);
  STAGE(1, 1);

  int cur = 0;
  for (int kt = 0; kt < NT; ++kt) {
    if (kt + 1 < NT) { asm volatile("s_waitcnt vmcnt(6)" ::: "memory"); }
    else             { asm volatile("s_waitcnt vmcnt(0)" ::: "memory"); }
    SCHB; SBAR;
    const short* Ad = As[cur];
    const short* Bd = Bs[cur];
    short8 a0, a1, a2, a3, a4, a5, a6, a7, b0, b1, b2, b3;
    a0 = LD8(Ad, abase + 0 * 512 + sx);
    a1 = LD8(Ad, abase + 1 * 512 + sx);
    b0 = LD8(Bd, bbase + 0 * 512 + sx);
    b1 = LD8(Bd, bbase + 1 * 512 + sx);
    b2 = LD8(Bd, bbase + 2 * 512 + sx);
    b3 = LD8(Bd, bbase + 3 * 512 + sx);
    a2 = LD8(Ad, abase + 2 * 512 + sx);
    a3 = LD8(Ad, abase + 3 * 512 + sx);
    a4 = LD8(Ad, abase + 4 * 512 + sx);
    a5 = LD8(Ad, abase + 5 * 512 + sx);
    a6 = LD8(Ad, abase + 6 * 512 + sx);
    a7 = LD8(Ad, abase + 7 * 512 + sx);
    SCHB;
    asm volatile("s_waitcnt lgkmcnt(6)" ::: "memory");
    SCHB;
    __builtin_amdgcn_s_setprio(1);
    MROW(0, a0) MROW(1, a1)
    __builtin_amdgcn_s_setprio(0);
    SCHB;
    asm volatile("s_waitcnt lgkmcnt(0)" ::: "memory");
    SCHB; SBAR;
    if (kt + 2 < NT) STAGE(kt + 2, cur);
    SCHB;
    __builtin_amdgcn_s_setprio(1);
    MROW(2, a2) MROW(3, a3) MROW(4, a4) MROW(5, a5) MROW(6, a6) MROW(7, a7)
    __builtin_amdgcn_s_setprio(0);
    SCHB;
    cur ^= 1;
  }

  float sv[4], qv[4];
#pragma unroll
  for (int ni = 0; ni < 4; ++ni) { sv[ni] = 0.f; qv[ni] = 0.f; }

#pragma unroll
  for (int mi = 0; mi < 8; ++mi) {
#pragma unroll
    for (int ni = 0; ni < 4; ++ni) {
#pragma unroll
      for (int j = 0; j < 4; ++j) {
        int r  = (int)row0 + wm * 128 + mi * 16 + lhi * 4 + j;
        int cc = (int)col0 + wc * 64 + ni * 16 + lr;
        float v = acc[mi][ni][j];
        sv[ni] += v; qv[ni] += v * v;
        int rr = r * 2 + bz;
        ((short*)Cout)[((size_t)(cc >> 9) << 19) + (size_t)rr * 512 + (cc & 511)] = f2bf(v);
      }
    }
  }

  {
    __syncthreads();
    float* redS = (float*)&As[0][0];
    float* redQ = redS + 1024;
    const int contrib = wm * 4 + lhi;
#pragma unroll
    for (int ni = 0; ni < 4; ++ni) {
      int ccl = wc * 64 + ni * 16 + lr;
      redS[ccl * 8 + contrib] = sv[ni];
      redQ[ccl * 8 + contrib] = qv[ni];
    }
    __syncthreads();
    if (tid < 128) {
      float S = 0.f, Q = 0.f;
#pragma unroll
      for (int i = 0; i < 8; ++i) { S += redS[tid * 8 + i]; Q += redQ[tid * 8 + i]; }
      float2 o; o.x = S; o.y = Q;
      P[(size_t)(bz * 2 + bx) * 16384 + col0 + tid] = o;
    }
  }
#undef MROW
#undef STAGE
}

// ======== 256x256 8-phase BT-GEMM (r8 structure, EPI1) — GEMM2 ============
// BK=64, 8 waves (2Mx4N), interleaved wave map; per K-tile 4 phases
// {ds_reads; stage 1 half; barrier; lgkm(0); 16 MFMA; barrier}; vmcnt(6)
// at ph3 only. relu -> z1t bf16. Measured ~37us on GEMM2's shape in r8.
__global__ __launch_bounds__(512, 2) void gemm2p8(
    const short* __restrict__ A, const short* __restrict__ B,
    short* __restrict__ Cout, int K, int NT, long strideA)
{
  __shared__ short As[2][16384];
  __shared__ short Bs[2][16384];
  const int tid = threadIdx.x;
  const int l   = tid & 63;
  const int w   = tid >> 6;        // wave 0..7
  const int wm  = w >> 2;          // 0..1
  const int wn  = w & 3;           // 0..3
  const int l7  = l & 7;
  const int lr  = l & 15;
  const int lhi = l >> 4;

  const int nwg = gridDim.x, q = nwg >> 3, orig = blockIdx.x;
  const int wgid = (orig & 7) * q + (orig >> 3);
  const int bx = wgid & 3, by = (wgid >> 2) & 3, bz = wgid >> 4;

  const long row0 = (long)bx * 256, col0 = (long)by * 256;
  const short* Ab = A + (size_t)bz * strideA + (size_t)row0 * K;
  const short* Bb = B + (size_t)col0 * K;

  const int rowb  = w * 8 + (l >> 3);
  const int colel = (l7 ^ (l >> 3)) * 8;
  const int abase = (wm * 16 + lr) * 64;
  const int bbase = (wn * 16 + lr) * 64;
  const int s0 = ((lhi    ) ^ l7) * 8;
  const int s1 = ((lhi + 4) ^ l7) * 8;

  f32x4 acc[8][4];
#pragma unroll
  for (int i = 0; i < 8; ++i)
#pragma unroll
    for (int j = 0; j < 4; ++j) acc[i][j] = (f32x4){0.f, 0.f, 0.f, 0.f};

#define ST_HALF(OPb, OPlds, T, H) do {                                       \
    const size_t ko_ = (size_t)(T) * 64 + colel;                             \
    const short* sb_ = (OPb) + (size_t)((H) * 128 + rowb) * K + ko_;         \
    short* db_ = &OPlds[(T) & 1][(H) * 8192 + w * 512 + l * 8];              \
    GLL(sb_, db_);                                                           \
    GLL(sb_ + (size_t)64 * K, db_ + 4096);                                   \
  } while (0)

#define QUAD16(MIH, A0, A1, A2, A3, B0, B1, B2, B3)                          \
    __builtin_amdgcn_s_setprio(1);                                           \
    acc[MIH+0][0]=MFMA(A0,B0,acc[MIH+0][0]); acc[MIH+0][1]=MFMA(A0,B1,acc[MIH+0][1]); \
    acc[MIH+0][2]=MFMA(A0,B2,acc[MIH+0][2]); acc[MIH+0][3]=MFMA(A0,B3,acc[MIH+0][3]); \
    acc[MIH+1][0]=MFMA(A1,B0,acc[MIH+1][0]); acc[MIH+1][1]=MFMA(A1,B1,acc[MIH+1][1]); \
    acc[MIH+1][2]=MFMA(A1,B2,acc[MIH+1][2]); acc[MIH+1][3]=MFMA(A1,B3,acc[MIH+1][3]); \
    acc[MIH+2][0]=MFMA(A2,B0,acc[MIH+2][0]); acc[MIH+2][1]=MFMA(A2,B1,acc[MIH+2][1]); \
    acc[MIH+2][2]=MFMA(A2,B2,acc[MIH+2][2]); acc[MIH+2][3]=MFMA(A2,B3,acc[MIH+2][3]); \
    acc[MIH+3][0]=MFMA(A3,B0,acc[MIH+3][0]); acc[MIH+3][1]=MFMA(A3,B1,acc[MIH+3][1]); \
    acc[MIH+3][2]=MFMA(A3,B2,acc[MIH+3][2]); acc[MIH+3][3]=MFMA(A3,B3,acc[MIH+3][3]); \
    __builtin_amdgcn_s_setprio(0);

#define LGKM0 asm volatile("s_waitcnt lgkmcnt(0)" ::: "memory")

  ST_HALF(Bb, Bs, 0, 0); ST_HALF(Bb, Bs, 0, 1);
  ST_HALF(Ab, As, 0, 0); ST_HALF(Ab, As, 0, 1);
  ST_HALF(Bb, Bs, 1, 0); ST_HALF(Bb, Bs, 1, 1);
  ST_HALF(Ab, As, 1, 0);
  asm volatile("s_waitcnt vmcnt(6)" ::: "memory");
  SBAR;

  short8 b00, b01, b10, b11, b20, b21, b30, b31;
  short8 a0, a1, a2, a3;
  int cur = 0;
  for (int kt = 0; kt < NT; ++kt) {
    const short* Ad = As[cur];
    const short* Bd = Bs[cur];

    a0 = LD8(Ad, 0 * 2048 + abase + s0);
    a1 = LD8(Ad, 1 * 2048 + abase + s0);
    a2 = LD8(Ad, 2 * 2048 + abase + s0);
    a3 = LD8(Ad, 3 * 2048 + abase + s0);
    b00 = LD8(Bd, bbase + s0);          b01 = LD8(Bd, bbase + s1);
    b10 = LD8(Bd, 4096 + bbase + s0);   b11 = LD8(Bd, 4096 + bbase + s1);
    b20 = LD8(Bd, 8192 + bbase + s0);
    b30 = LD8(Bd, 12288 + bbase + s0);
    if (kt + 1 < NT) ST_HALF(Ab, As, kt + 1, 1);
    SCHB; SBAR;
    LGKM0; SCHB;
    QUAD16(0, a0, a1, a2, a3, b00, b10, b20, b30)
    SCHB; SBAR;

    a0 = LD8(Ad, 8192 + 0 * 2048 + abase + s0);
    a1 = LD8(Ad, 8192 + 1 * 2048 + abase + s0);
    a2 = LD8(Ad, 8192 + 2 * 2048 + abase + s0);
    a3 = LD8(Ad, 8192 + 3 * 2048 + abase + s0);
    b21 = LD8(Bd, 8192 + bbase + s1);
    b31 = LD8(Bd, 12288 + bbase + s1);
    if (kt + 2 < NT) ST_HALF(Bb, Bs, kt + 2, 0);
    SCHB; SBAR;
    LGKM0; SCHB;
    QUAD16(4, a0, a1, a2, a3, b00, b10, b20, b30)
    SCHB; SBAR;

    a0 = LD8(Ad, 0 * 2048 + abase + s1);
    a1 = LD8(Ad, 1 * 2048 + abase + s1);
    a2 = LD8(Ad, 2 * 2048 + abase + s1);
    a3 = LD8(Ad, 3 * 2048 + abase + s1);
    if (kt + 2 < NT) ST_HALF(Bb, Bs, kt + 2, 1);
    SCHB; SBAR;
    LGKM0; SCHB;
    QUAD16(0, a0, a1, a2, a3, b01, b11, b21, b31)
    SCHB; SBAR;

    a0 = LD8(Ad, 8192 + 0 * 2048 + abase + s1);
    a1 = LD8(Ad, 8192 + 1 * 2048 + abase + s1);
    a2 = LD8(Ad, 8192 + 2 * 2048 + abase + s1);
    a3 = LD8(Ad, 8192 + 3 * 2048 + abase + s1);
    if (kt + 2 < NT) ST_HALF(Ab, As, kt + 2, 0);
    if (kt + 2 < NT)      { asm volatile("s_waitcnt vmcnt(6)" ::: "memory"); }
    else if (kt + 1 < NT) { asm volatile("s_waitcnt vmcnt(0)" ::: "memory"); }
    SCHB; SBAR;
    LGKM0; SCHB;
    QUAD16(4, a0, a1, a2, a3, b01, b11, b21, b31)
    SCHB; SBAR;

    cur ^= 1;
  }

#pragma unroll
  for (int mi = 0; mi < 8; ++mi) {
#pragma unroll
    for (int ni = 0; ni < 4; ++ni) {
#pragma unroll
      for (int j = 0; j < 4; ++j) {
        int r  = (int)row0 + (mi >> 2) * 128 + (mi & 3) * 32 + wm * 16 + lhi * 4 + j;
        int cc = (int)col0 + (ni >> 1) * 128 + (ni & 1) * 64 + wn * 16 + lr;
        float v = acc[mi][ni][j];
        Cout[(size_t)bz * 1048576 + (size_t)r * 1024 + cc] = f2bf(v > 0.f ? v : 0.f);
      }
    }
  }
#undef QUAD16
#undef ST_HALF
#undef LGKM0
}

// ======== 128x128 dbuf BT-GEMM, 4 waves, 2 blocks/CU (r9) — GEMM3 =========
__global__ __launch_bounds__(256, 2) void gemm3k(
    const short* __restrict__ A, const short* __restrict__ B,
    float* __restrict__ Cout, const float* __restrict__ X,
    int K, int NT, long strideB)
{
  __shared__ short As[2][8192];
  __shared__ short Bs[2][8192];
  const int tid = threadIdx.x;
  const int l   = tid & 63;
  const int w   = tid >> 6;
  const int wm  = w >> 1;
  const int wc  = w & 1;
  const int l7  = l & 7;
  const int lr  = l & 15;
  const int lhi = l >> 4;

  const int nwg = gridDim.x, q = nwg >> 3, orig = blockIdx.x;
  const int wgid = (orig & 7) * q + (orig >> 3);
  int bx = wgid & 3, by = (wgid >> 2) & 7, bz = wgid >> 5;

  const long row0 = (long)bx * 128, col0 = (long)by * 128;
  const short* Ab = A + (size_t)row0 * K;
  const short* Bb = B + (size_t)bz * strideB + (size_t)col0 * K;

  const int rowb  = tid >> 3;
  const int colel = ((tid & 7) ^ ((tid >> 3) & 7)) * 8;
  const int abase = (wm * 64 + lr) * 64;
  const int bbase = (wc * 64 + lr) * 64;
  const int s0 = ((lhi    ) ^ l7) * 8;
  const int s1 = ((lhi + 4) ^ l7) * 8;

  f32x4 acc[4][4];
#pragma unroll
  for (int i = 0; i < 4; ++i)
#pragma unroll
    for (int j = 0; j < 4; ++j) acc[i][j] = (f32x4){0.f, 0.f, 0.f, 0.f};

#define STAGE(KT, D) do {                                                    \
    const size_t ko_ = (size_t)(KT) * 64 + colel;                            \
    _Pragma("unroll")                                                        \
    for (int r_ = 0; r_ < 4; ++r_)                                           \
      GLL(Ab + (size_t)(r_ * 32 + rowb) * K + ko_,                           \
          &As[D][(r_ * 32 + rowb) * 64 + (tid & 7) * 8]);                    \
    _Pragma("unroll")                                                        \
    for (int r_ = 0; r_ < 4; ++r_)                                           \
      GLL(Bb + (size_t)(r_ * 32 + rowb) * K + ko_,                           \
          &Bs[D][(r_ * 32 + rowb) * 64 + (tid & 7) * 8]);                    \
  } while (0)

#define MFMA16(A0, A1, A2, A3, B0, B1, B2, B3)                               \
    __builtin_amdgcn_s_setprio(1);                                           \
    acc[0][0]=MFMA(A0,B0,acc[0][0]); acc[0][1]=MFMA(A0,B1,acc[0][1]);        \
    acc[0][2]=MFMA(A0,B2,acc[0][2]); acc[0][3]=MFMA(A0,B3,acc[0][3]);        \
    acc[1][0]=MFMA(A1,B0,acc[1][0]); acc[1][1]=MFMA(A1,B1,acc[1][1]);        \
    acc[1][2]=MFMA(A1,B2,acc[1][2]); acc[1][3]=MFMA(A1,B3,acc[1][3]);        \
    acc[2][0]=MFMA(A2,B0,acc[2][0]); acc[2][1]=MFMA(A2,B1,acc[2][1]);        \
    acc[2][2]=MFMA(A2,B2,acc[2][2]); acc[2][3]=MFMA(A2,B3,acc[2][3]);        \
    acc[3][0]=MFMA(A3,B0,acc[3][0]); acc[3][1]=MFMA(A3,B1,acc[3][1]);        \
    acc[3][2]=MFMA(A3,B2,acc[3][2]); acc[3][3]=MFMA(A3,B3,acc[3][3]);        \
    __builtin_amdgcn_s_setprio(0);

  STAGE(0, 0);
  STAGE(1, 1);

  int cur = 0;
  for (int kt = 0; kt < NT; ++kt) {
    if (kt + 1 < NT) { asm volatile("s_waitcnt vmcnt(8)" ::: "memory"); }
    else             { asm volatile("s_waitcnt vmcnt(0)" ::: "memory"); }
    SCHB; SBAR;
    const short* Ad = As[cur];
    const short* Bd = Bs[cur];
    short8 a00, a01, a02, a03, b00, b01, b02, b03;
    short8 a10, a11, a12, a13, b10, b11, b12, b13;
    a00 = LD8(Ad, abase + 0 * 1024 + s0);
    a01 = LD8(Ad, abase + 1 * 1024 + s0);
    a02 = LD8(Ad, abase + 2 * 1024 + s0);
    a03 = LD8(Ad, abase + 3 * 1024 + s0);
    b00 = LD8(Bd, bbase + 0 * 1024 + s0);
    b01 = LD8(Bd, bbase + 1 * 1024 + s0);
    b02 = LD8(Bd, bbase + 2 * 1024 + s0);
    b03 = LD8(Bd, bbase + 3 * 1024 + s0);
    a10 = LD8(Ad, abase + 0 * 1024 + s1);
    a11 = LD8(Ad, abase + 1 * 1024 + s1);
    a12 = LD8(Ad, abase + 2 * 1024 + s1);
    a13 = LD8(Ad, abase + 3 * 1024 + s1);
    b10 = LD8(Bd, bbase + 0 * 1024 + s1);
    b11 = LD8(Bd, bbase + 1 * 1024 + s1);
    b12 = LD8(Bd, bbase + 2 * 1024 + s1);
    b13 = LD8(Bd, bbase + 3 * 1024 + s1);
    SCHB;
    asm volatile("s_waitcnt lgkmcnt(8)" ::: "memory");
    SCHB;
    MFMA16(a00, a01, a02, a03, b00, b01, b02, b03)
    SCHB;
    asm volatile("s_waitcnt lgkmcnt(0)" ::: "memory");
    SCHB; SBAR;
    if (kt + 2 < NT) STAGE(kt + 2, cur);
    SCHB;
    MFMA16(a10, a11, a12, a13, b10, b11, b12, b13)
    SCHB;
    cur ^= 1;
  }

#pragma unroll
  for (int mi = 0; mi < 4; ++mi) {
#pragma unroll
    for (int ni = 0; ni < 4; ++ni) {
#pragma unroll
      for (int j = 0; j < 4; ++j) {
        int r  = (int)row0 + wm * 64 + mi * 16 + lhi * 4 + j;
        int cc = (int)col0 + wc * 64 + ni * 16 + lr;
        float v = acc[mi][ni][j];
        size_t idx = (size_t)bz * 524288 + (size_t)r * 1024 + cc;
        float g = 1.f / (1.f + __expf(-v));
        Cout[idx] = X[idx] * g;
      }
    }
  }
#undef MFMA16
#undef STAGE
#undef GLL
#undef LD8
#undef MFMA
#undef SBAR
#undef SCHB
}

extern "C" void kernel_launch(void* const* d_in, const int* in_sizes, int n_in,
                              void* d_out, int out_size, void* d_ws, size_t ws_size,
                              hipStream_t stream) {
  const float* x    = (const float*)d_in[0];   // [32,512,1024]
  const float* w1   = (const float*)d_in[1];   // [1024,512]
  const float* w2   = (const float*)d_in[2];   // [512,1024]
  const float* ln_w = (const float*)d_in[3];   // [1024]
  const float* ln_b = (const float*)d_in[4];   // [1024]
  float* out = (float*)d_out;

  char* ws = (char*)d_ws;
  short* Deo    = (short*)(ws);                  //  1,048,576 B [2][512][512]
  short* w1_bf  = (short*)(ws + 1048576);        //  1,048,576 B
  short* w2_bf  = (short*)(ws + 2097152);        //  1,048,576 B
  short* freqT  = (short*)(ws + 3145728);        // 33,554,432 B [b][k][c]
  short* z1t    = (short*)(ws + 36700160);       // 67,108,864 B [b][p][o]
  short* eo     = z1t;                           // e/o alias z1t (dead by GEMM2)
  float2* part  = (float2*)(ws + 103809024);     //    524,288 B [4][16384]
  float2* musd  = (float2*)(ws + 104857600);     //    131,072 B [16384]
  // total ~105 MB

  prep_eo<<<dim3(8192), dim3(256), 0, stream>>>(x, eo);
  cast_w<<<dim3(1024), dim3(256), 0, stream>>>(w1, w2, w1_bf, w2_bf);
  build_Deo<<<dim3(2048), dim3(256), 0, stream>>>(Deo);

  // GEMM1 (even/odd): C[k',(b,c)] = sum_n Deo[p][k',n]*eo[p][(b,c),n]
  // -> freqT rows 2k'+p, + LN partials. K=512, NT=16.
  gemm1F<<<dim3(512), dim3(256), 0, stream>>>(
      Deo, eo, (void*)freqT, part, 512, 16, 262144, 8388608);

  // LN stats: fold 4 partials -> (mu, rstd) per (b,c)
  ln_stats<<<dim3(64), dim3(256), 0, stream>>>(part, musd);

  // LN apply: normalize freqT in place (streaming, vectorized)
  ln_apply<<<dim3(8192), dim3(256), 0, stream>>>(freqT, musd, ln_w, ln_b);

  // GEMM2 (8-phase 256^2): C[p,o] = sum_c Ht[b][p,c]*w1[o,c], relu -> z1t
  gemm2p8<<<dim3(512), dim3(512), 0, stream>>>(
      freqT, w1_bf, z1t, 512, 8, 524288);

  // GEMM3: C[o2,p] = sum_j w2[o2,j]*z1t[b][p,j]; out = x * sigmoid(C)
  gemm3k<<<dim3(1024), dim3(256), 0, stream>>>(
      w2_bf, z1t, out, x, 1024, 16, 1048576);
}

// Round 19
// 156.760 us; speedup vs baseline: 1.0527x; 1.0183x over previous
//
#include <hip/hip_runtime.h>
#include <hip/hip_bf16.h>
#include <math.h>

typedef short short8 __attribute__((ext_vector_type(8)));
typedef short short4v __attribute__((ext_vector_type(4)));
typedef float f32x4 __attribute__((ext_vector_type(4)));

__device__ __forceinline__ short f2bf(float f) {
  union { float f; unsigned u; } v; v.f = f;
  unsigned r = v.u + 0x7FFFu + ((v.u >> 16) & 1u);
  return (short)(r >> 16);
}
__device__ __forceinline__ float bf2f(short s) {
  union { unsigned u; float f; } v; v.u = ((unsigned)(unsigned short)s) << 16;
  return v.f;
}

// -------- fused weight cast: w1 then w2, 4 elems/thread -------------------
__global__ __launch_bounds__(256) void cast_w(const float* __restrict__ w1,
                                              const float* __restrict__ w2,
                                              short* __restrict__ w1_bf,
                                              short* __restrict__ w2_bf) {
  int i = blockIdx.x * blockDim.x + threadIdx.x;   // 262144 total (x4 elems)
  const float* src = (i < 131072) ? w1 : w2;
  short* dst = (i < 131072) ? w1_bf : w2_bf;
  int j = (i < 131072) ? i : i - 131072;
  float4 v = ((const float4*)src)[j];
  short4v o;
  o.x = f2bf(v.x); o.y = f2bf(v.y); o.z = f2bf(v.z); o.w = f2bf(v.w);
  ((short4v*)dst)[j] = o;
}

// -------- DCT even/odd prep: e[n]=x[n]+x[1023-n], o[n]=x[n]-x[1023-n] -----
__global__ __launch_bounds__(256) void prep_eo(const float* __restrict__ x,
                                               short* __restrict__ eo) {
  int t = blockIdx.x * 256 + threadIdx.x;     // 16384 * 128
  int bc = t >> 7, n0 = (t & 127) * 4;        // n0 in [0,512)
  const float* xr = x + (size_t)bc * 1024;
  float4 f = *(const float4*)(xr + n0);
  float4 r = *(const float4*)(xr + 1020 - n0);
  short4v ef, of;
  ef.x = f2bf(f.x + r.w); ef.y = f2bf(f.y + r.z); ef.z = f2bf(f.z + r.y); ef.w = f2bf(f.w + r.x);
  of.x = f2bf(f.x - r.w); of.y = f2bf(f.y - r.z); of.z = f2bf(f.z - r.y); of.w = f2bf(f.w - r.x);
  *(short4v*)&eo[(size_t)bc * 512 + n0] = ef;
  *(short4v*)&eo[8388608 + (size_t)bc * 512 + n0] = of;
}

// -------- Deo[parity][k'][n] = 2*cos(pi/2048 * (2k'+parity) * (2n+1)) -----
__global__ __launch_bounds__(256) void build_Deo(short* __restrict__ D) {
  int t = blockIdx.x * 256 + threadIdx.x;     // 2*512*512 = 524288
  int parity = t >> 18, rem = t & 262143;
  int k2 = rem >> 9, n = rem & 511;
  const float s = 1.5339807878856412e-03f;    // pi/2048
  float arg = (s * (float)(2 * k2 + parity)) * (float)(2 * n + 1);
  D[t] = f2bf(2.0f * cosf(arg));
}

// -------- fold 4 row-block partials -> per-(b,c) mu, rstd -----------------
__global__ __launch_bounds__(256) void ln_stats(const float2* __restrict__ partial,
                                                float2* __restrict__ musd) {
  int n = blockIdx.x * 256 + threadIdx.x;   // 16384
  float S = 0.f, Q = 0.f;
#pragma unroll
  for (int r = 0; r < 4; ++r) {
    float2 p = partial[(size_t)r * 16384 + n];
    S += p.x; Q += p.y;
  }
  float mu  = S * (1.f / 1024.f);
  float var = Q * (1.f / 1024.f) - mu * mu;   // biased, like nn.LayerNorm
  float2 o; o.x = mu; o.y = rsqrtf(var + 1e-6f);
  musd[n] = o;
}

// -------- streaming LN apply: freqT[b][k][c] in place, short8/thread ------
__global__ __launch_bounds__(256) void ln_apply(short* __restrict__ freqT,
                                                const float2* __restrict__ musd,
                                                const float* __restrict__ lnw,
                                                const float* __restrict__ lnb) {
  int t = blockIdx.x * 256 + threadIdx.x;
  int c8 = t & 63;
  int k  = (t >> 6) & 1023;
  int b  = t >> 16;
  size_t idx = ((size_t)b << 19) + (size_t)k * 512 + (size_t)c8 * 8;
  short8 v = *(const short8*)&freqT[idx];
  float w  = lnw[k];
  float bb = lnb[k];
  const float2* ms = &musd[b * 512 + c8 * 8];
  short8 o;
#pragma unroll
  for (int j = 0; j < 8; ++j) {
    float f = bf2f(v[j]);
    float2 m = ms[j];
    o[j] = f2bf((f - m.x) * m.y * w + bb);
  }
  *(short8*)&freqT[idx] = o;
}

// ======== 256x128 BK=32 dbuf BT-GEMM (r13 structure) — GEMM1 ==============
// Per-wave output 128x64 (acc[8][4]); LDS 48KB -> 2 blocks/CU; counted
// vmcnt(6)/lgkm(6) schedule; swizzle phys slot = logical ^ ((row>>1)&3).
// A=Deo(k'), B=eo; bz=parity; out row=2r+bz; LN partials slot bz*2+bx.
__global__ __launch_bounds__(256, 2) void gemm1F(
    const short* __restrict__ A, const short* __restrict__ B,
    void* __restrict__ Cout, float2* __restrict__ P,
    int K, int NT, long strideA, long strideB)
{
  __shared__ short As[2][8192];    // 256 rows x 32 k
  __shared__ short Bs[2][4096];    // 128 rows x 32 k
  const int tid = threadIdx.x;     // 256
  const int l   = tid & 63;
  const int w   = tid >> 6;        // wave 0..3
  const int wm  = w >> 1;
  const int wc  = w & 1;
  const int lr  = l & 15;
  const int lhi = l >> 4;

  const int nwg = gridDim.x, q = nwg >> 3, orig = blockIdx.x;
  const int wgid = (orig & 7) * q + (orig >> 3);
  int bx = wgid & 1, bz = (wgid >> 1) & 1, by = wgid >> 2;

  const long row0 = (long)bx * 256, col0 = (long)by * 128;
  const short* Ab = A + (size_t)bz * strideA + (size_t)row0 * K;
  const short* Bb = B + (size_t)bz * strideB + (size_t)col0 * K;

  const int sx    = (lhi ^ ((lr >> 1) & 3)) * 8;
  const int abase = (wm * 128 + lr) * 32;
  const int bbase = (wc * 64  + lr) * 32;

  f32x4 acc[8][4];
#pragma unroll
  for (int i = 0; i < 8; ++i)
#pragma unroll
    for (int j = 0; j < 4; ++j) acc[i][j] = (f32x4){0.f, 0.f, 0.f, 0.f};

#define GLL(SRC, DST) __builtin_amdgcn_global_load_lds(                      \
      (const __attribute__((address_space(1))) void*)(SRC),                  \
      (__attribute__((address_space(3))) void*)(DST), 16, 0, 0)

#define STAGE(KT, D) do {                                                    \
    const size_t kb_ = (size_t)(KT) * 32;                                    \
    _Pragma("unroll")                                                        \
    for (int r_ = 0; r_ < 4; ++r_) {                                         \
      int c_ = r_ * 256 + tid; int row_ = c_ >> 2; int sl_ = c_ & 3;         \
      int sc_ = (sl_ ^ ((row_ >> 1) & 3)) * 8;                               \
      GLL(Ab + (size_t)row_ * K + kb_ + sc_, &As[D][row_ * 32 + sl_ * 8]);   \
    }                                                                        \
    _Pragma("unroll")                                                        \
    for (int r_ = 0; r_ < 2; ++r_) {                                         \
      int c_ = r_ * 256 + tid; int row_ = c_ >> 2; int sl_ = c_ & 3;         \
      int sc_ = (sl_ ^ ((row_ >> 1) & 3)) * 8;                               \
      GLL(Bb + (size_t)row_ * K + kb_ + sc_, &Bs[D][row_ * 32 + sl_ * 8]);   \
    }                                                                        \
  } while (0)

#define LD8(PTR, OFF) (*(const short8*)&(PTR)[OFF])
#define MFMA(AV, BV, C) __builtin_amdgcn_mfma_f32_16x16x32_bf16(AV, BV, C, 0, 0, 0)
#define SBAR __builtin_amdgcn_s_barrier()
#define SCHB __builtin_amdgcn_sched_barrier(0)

#define MROW(MI, AV)                                                         \
    acc[MI][0] = MFMA(AV, b0, acc[MI][0]);                                   \
    acc[MI][1] = MFMA(AV, b1, acc[MI][1]);                                   \
    acc[MI][2] = MFMA(AV, b2, acc[MI][2]);                                   \
    acc[MI][3] = MFMA(AV, b3, acc[MI][3]);

  STAGE(0, 0);
  STAGE(1, 1);

  int cur = 0;
  for (int kt = 0; kt < NT; ++kt) {
    if (kt + 1 < NT) { asm volatile("s_waitcnt vmcnt(6)" ::: "memory"); }
    else             { asm volatile("s_waitcnt vmcnt(0)" ::: "memory"); }
    SCHB; SBAR;
    const short* Ad = As[cur];
    const short* Bd = Bs[cur];
    short8 a0, a1, a2, a3, a4, a5, a6, a7, b0, b1, b2, b3;
    a0 = LD8(Ad, abase + 0 * 512 + sx);
    a1 = LD8(Ad, abase + 1 * 512 + sx);
    b0 = LD8(Bd, bbase + 0 * 512 + sx);
    b1 = LD8(Bd, bbase + 1 * 512 + sx);
    b2 = LD8(Bd, bbase + 2 * 512 + sx);
    b3 = LD8(Bd, bbase + 3 * 512 + sx);
    a2 = LD8(Ad, abase + 2 * 512 + sx);
    a3 = LD8(Ad, abase + 3 * 512 + sx);
    a4 = LD8(Ad, abase + 4 * 512 + sx);
    a5 = LD8(Ad, abase + 5 * 512 + sx);
    a6 = LD8(Ad, abase + 6 * 512 + sx);
    a7 = LD8(Ad, abase + 7 * 512 + sx);
    SCHB;
    asm volatile("s_waitcnt lgkmcnt(6)" ::: "memory");
    SCHB;
    __builtin_amdgcn_s_setprio(1);
    MROW(0, a0) MROW(1, a1)
    __builtin_amdgcn_s_setprio(0);
    SCHB;
    asm volatile("s_waitcnt lgkmcnt(0)" ::: "memory");
    SCHB; SBAR;
    if (kt + 2 < NT) STAGE(kt + 2, cur);
    SCHB;
    __builtin_amdgcn_s_setprio(1);
    MROW(2, a2) MROW(3, a3) MROW(4, a4) MROW(5, a5) MROW(6, a6) MROW(7, a7)
    __builtin_amdgcn_s_setprio(0);
    SCHB;
    cur ^= 1;
  }

  float sv[4], qv[4];
#pragma unroll
  for (int ni = 0; ni < 4; ++ni) { sv[ni] = 0.f; qv[ni] = 0.f; }

#pragma unroll
  for (int mi = 0; mi < 8; ++mi) {
#pragma unroll
    for (int ni = 0; ni < 4; ++ni) {
#pragma unroll
      for (int j = 0; j < 4; ++j) {
        int r  = (int)row0 + wm * 128 + mi * 16 + lhi * 4 + j;
        int cc = (int)col0 + wc * 64 + ni * 16 + lr;
        float v = acc[mi][ni][j];
        sv[ni] += v; qv[ni] += v * v;
        int rr = r * 2 + bz;
        ((short*)Cout)[((size_t)(cc >> 9) << 19) + (size_t)rr * 512 + (cc & 511)] = f2bf(v);
      }
    }
  }

  {
    __syncthreads();
    float* redS = (float*)&As[0][0];
    float* redQ = redS + 1024;
    const int contrib = wm * 4 + lhi;
#pragma unroll
    for (int ni = 0; ni < 4; ++ni) {
      int ccl = wc * 64 + ni * 16 + lr;
      redS[ccl * 8 + contrib] = sv[ni];
      redQ[ccl * 8 + contrib] = qv[ni];
    }
    __syncthreads();
    if (tid < 128) {
      float S = 0.f, Q = 0.f;
#pragma unroll
      for (int i = 0; i < 8; ++i) { S += redS[tid * 8 + i]; Q += redQ[tid * 8 + i]; }
      float2 o; o.x = S; o.y = Q;
      P[(size_t)(bz * 2 + bx) * 16384 + col0 + tid] = o;
    }
  }
#undef MROW
#undef STAGE
}

// ======== 256x256 8-phase BT-GEMM (r8 structure, EPI1) — GEMM2 ============
// BK=64, 8 waves (2Mx4N), interleaved wave map; per K-tile 4 phases
// {ds_reads; stage 1 half; barrier; lgkm(0); 16 MFMA; barrier}; vmcnt(6)
// at ph3 only. relu -> z1t bf16. Measured ~37us on GEMM2's shape in r8.
__global__ __launch_bounds__(512, 2) void gemm2p8(
    const short* __restrict__ A, const short* __restrict__ B,
    short* __restrict__ Cout, int K, int NT, long strideA)
{
  __shared__ short As[2][16384];
  __shared__ short Bs[2][16384];
  const int tid = threadIdx.x;
  const int l   = tid & 63;
  const int w   = tid >> 6;        // wave 0..7
  const int wm  = w >> 2;          // 0..1
  const int wn  = w & 3;           // 0..3
  const int l7  = l & 7;
  const int lr  = l & 15;
  const int lhi = l >> 4;

  const int nwg = gridDim.x, q = nwg >> 3, orig = blockIdx.x;
  const int wgid = (orig & 7) * q + (orig >> 3);
  const int bx = wgid & 3, by = (wgid >> 2) & 3, bz = wgid >> 4;

  const long row0 = (long)bx * 256, col0 = (long)by * 256;
  const short* Ab = A + (size_t)bz * strideA + (size_t)row0 * K;
  const short* Bb = B + (size_t)col0 * K;

  const int rowb  = w * 8 + (l >> 3);
  const int colel = (l7 ^ (l >> 3)) * 8;
  const int abase = (wm * 16 + lr) * 64;
  const int bbase = (wn * 16 + lr) * 64;
  const int s0 = ((lhi    ) ^ l7) * 8;
  const int s1 = ((lhi + 4) ^ l7) * 8;

  f32x4 acc[8][4];
#pragma unroll
  for (int i = 0; i < 8; ++i)
#pragma unroll
    for (int j = 0; j < 4; ++j) acc[i][j] = (f32x4){0.f, 0.f, 0.f, 0.f};

#define ST_HALF(OPb, OPlds, T, H) do {                                       \
    const size_t ko_ = (size_t)(T) * 64 + colel;                             \
    const short* sb_ = (OPb) + (size_t)((H) * 128 + rowb) * K + ko_;         \
    short* db_ = &OPlds[(T) & 1][(H) * 8192 + w * 512 + l * 8];              \
    GLL(sb_, db_);                                                           \
    GLL(sb_ + (size_t)64 * K, db_ + 4096);                                   \
  } while (0)

#define QUAD16(MIH, A0, A1, A2, A3, B0, B1, B2, B3)                          \
    __builtin_amdgcn_s_setprio(1);                                           \
    acc[MIH+0][0]=MFMA(A0,B0,acc[MIH+0][0]); acc[MIH+0][1]=MFMA(A0,B1,acc[MIH+0][1]); \
    acc[MIH+0][2]=MFMA(A0,B2,acc[MIH+0][2]); acc[MIH+0][3]=MFMA(A0,B3,acc[MIH+0][3]); \
    acc[MIH+1][0]=MFMA(A1,B0,acc[MIH+1][0]); acc[MIH+1][1]=MFMA(A1,B1,acc[MIH+1][1]); \
    acc[MIH+1][2]=MFMA(A1,B2,acc[MIH+1][2]); acc[MIH+1][3]=MFMA(A1,B3,acc[MIH+1][3]); \
    acc[MIH+2][0]=MFMA(A2,B0,acc[MIH+2][0]); acc[MIH+2][1]=MFMA(A2,B1,acc[MIH+2][1]); \
    acc[MIH+2][2]=MFMA(A2,B2,acc[MIH+2][2]); acc[MIH+2][3]=MFMA(A2,B3,acc[MIH+2][3]); \
    acc[MIH+3][0]=MFMA(A3,B0,acc[MIH+3][0]); acc[MIH+3][1]=MFMA(A3,B1,acc[MIH+3][1]); \
    acc[MIH+3][2]=MFMA(A3,B2,acc[MIH+3][2]); acc[MIH+3][3]=MFMA(A3,B3,acc[MIH+3][3]); \
    __builtin_amdgcn_s_setprio(0);

#define LGKM0 asm volatile("s_waitcnt lgkmcnt(0)" ::: "memory")

  ST_HALF(Bb, Bs, 0, 0); ST_HALF(Bb, Bs, 0, 1);
  ST_HALF(Ab, As, 0, 0); ST_HALF(Ab, As, 0, 1);
  ST_HALF(Bb, Bs, 1, 0); ST_HALF(Bb, Bs, 1, 1);
  ST_HALF(Ab, As, 1, 0);
  asm volatile("s_waitcnt vmcnt(6)" ::: "memory");
  SBAR;

  short8 b00, b01, b10, b11, b20, b21, b30, b31;
  short8 a0, a1, a2, a3;
  int cur = 0;
  for (int kt = 0; kt < NT; ++kt) {
    const short* Ad = As[cur];
    const short* Bd = Bs[cur];

    a0 = LD8(Ad, 0 * 2048 + abase + s0);
    a1 = LD8(Ad, 1 * 2048 + abase + s0);
    a2 = LD8(Ad, 2 * 2048 + abase + s0);
    a3 = LD8(Ad, 3 * 2048 + abase + s0);
    b00 = LD8(Bd, bbase + s0);          b01 = LD8(Bd, bbase + s1);
    b10 = LD8(Bd, 4096 + bbase + s0);   b11 = LD8(Bd, 4096 + bbase + s1);
    b20 = LD8(Bd, 8192 + bbase + s0);
    b30 = LD8(Bd, 12288 + bbase + s0);
    if (kt + 1 < NT) ST_HALF(Ab, As, kt + 1, 1);
    SCHB; SBAR;
    LGKM0; SCHB;
    QUAD16(0, a0, a1, a2, a3, b00, b10, b20, b30)
    SCHB; SBAR;

    a0 = LD8(Ad, 8192 + 0 * 2048 + abase + s0);
    a1 = LD8(Ad, 8192 + 1 * 2048 + abase + s0);
    a2 = LD8(Ad, 8192 + 2 * 2048 + abase + s0);
    a3 = LD8(Ad, 8192 + 3 * 2048 + abase + s0);
    b21 = LD8(Bd, 8192 + bbase + s1);
    b31 = LD8(Bd, 12288 + bbase + s1);
    if (kt + 2 < NT) ST_HALF(Bb, Bs, kt + 2, 0);
    SCHB; SBAR;
    LGKM0; SCHB;
    QUAD16(4, a0, a1, a2, a3, b00, b10, b20, b30)
    SCHB; SBAR;

    a0 = LD8(Ad, 0 * 2048 + abase + s1);
    a1 = LD8(Ad, 1 * 2048 + abase + s1);
    a2 = LD8(Ad, 2 * 2048 + abase + s1);
    a3 = LD8(Ad, 3 * 2048 + abase + s1);
    if (kt + 2 < NT) ST_HALF(Bb, Bs, kt + 2, 1);
    SCHB; SBAR;
    LGKM0; SCHB;
    QUAD16(0, a0, a1, a2, a3, b01, b11, b21, b31)
    SCHB; SBAR;

    a0 = LD8(Ad, 8192 + 0 * 2048 + abase + s1);
    a1 = LD8(Ad, 8192 + 1 * 2048 + abase + s1);
    a2 = LD8(Ad, 8192 + 2 * 2048 + abase + s1);
    a3 = LD8(Ad, 8192 + 3 * 2048 + abase + s1);
    if (kt + 2 < NT) ST_HALF(Ab, As, kt + 2, 0);
    if (kt + 2 < NT)      { asm volatile("s_waitcnt vmcnt(6)" ::: "memory"); }
    else if (kt + 1 < NT) { asm volatile("s_waitcnt vmcnt(0)" ::: "memory"); }
    SCHB; SBAR;
    LGKM0; SCHB;
    QUAD16(4, a0, a1, a2, a3, b01, b11, b21, b31)
    SCHB; SBAR;

    cur ^= 1;
  }

#pragma unroll
  for (int mi = 0; mi < 8; ++mi) {
#pragma unroll
    for (int ni = 0; ni < 4; ++ni) {
#pragma unroll
      for (int j = 0; j < 4; ++j) {
        int r  = (int)row0 + (mi >> 2) * 128 + (mi & 3) * 32 + wm * 16 + lhi * 4 + j;
        int cc = (int)col0 + (ni >> 1) * 128 + (ni & 1) * 64 + wn * 16 + lr;
        float v = acc[mi][ni][j];
        Cout[(size_t)bz * 1048576 + (size_t)r * 1024 + cc] = f2bf(v > 0.f ? v : 0.f);
      }
    }
  }
#undef QUAD16
#undef ST_HALF
#undef LGKM0
}

// ======== 128x128 dbuf BT-GEMM, 4 waves, 2 blocks/CU (r9) — GEMM3 =========
__global__ __launch_bounds__(256, 2) void gemm3k(
    const short* __restrict__ A, const short* __restrict__ B,
    float* __restrict__ Cout, const float* __restrict__ X,
    int K, int NT, long strideB)
{
  __shared__ short As[2][8192];
  __shared__ short Bs[2][8192];
  const int tid = threadIdx.x;
  const int l   = tid & 63;
  const int w   = tid >> 6;
  const int wm  = w >> 1;
  const int wc  = w & 1;
  const int l7  = l & 7;
  const int lr  = l & 15;
  const int lhi = l >> 4;

  const int nwg = gridDim.x, q = nwg >> 3, orig = blockIdx.x;
  const int wgid = (orig & 7) * q + (orig >> 3);
  int bx = wgid & 3, by = (wgid >> 2) & 7, bz = wgid >> 5;

  const long row0 = (long)bx * 128, col0 = (long)by * 128;
  const short* Ab = A + (size_t)row0 * K;
  const short* Bb = B + (size_t)bz * strideB + (size_t)col0 * K;

  const int rowb  = tid >> 3;
  const int colel = ((tid & 7) ^ ((tid >> 3) & 7)) * 8;
  const int abase = (wm * 64 + lr) * 64;
  const int bbase = (wc * 64 + lr) * 64;
  const int s0 = ((lhi    ) ^ l7) * 8;
  const int s1 = ((lhi + 4) ^ l7) * 8;

  f32x4 acc[4][4];
#pragma unroll
  for (int i = 0; i < 4; ++i)
#pragma unroll
    for (int j = 0; j < 4; ++j) acc[i][j] = (f32x4){0.f, 0.f, 0.f, 0.f};

#define STAGE(KT, D) do {                                                    \
    const size_t ko_ = (size_t)(KT) * 64 + colel;                            \
    _Pragma("unroll")                                                        \
    for (int r_ = 0; r_ < 4; ++r_)                                           \
      GLL(Ab + (size_t)(r_ * 32 + rowb) * K + ko_,                           \
          &As[D][(r_ * 32 + rowb) * 64 + (tid & 7) * 8]);                    \
    _Pragma("unroll")                                                        \
    for (int r_ = 0; r_ < 4; ++r_)                                           \
      GLL(Bb + (size_t)(r_ * 32 + rowb) * K + ko_,                           \
          &Bs[D][(r_ * 32 + rowb) * 64 + (tid & 7) * 8]);                    \
  } while (0)

#define MFMA16(A0, A1, A2, A3, B0, B1, B2, B3)                               \
    __builtin_amdgcn_s_setprio(1);                                           \
    acc[0][0]=MFMA(A0,B0,acc[0][0]); acc[0][1]=MFMA(A0,B1,acc[0][1]);        \
    acc[0][2]=MFMA(A0,B2,acc[0][2]); acc[0][3]=MFMA(A0,B3,acc[0][3]);        \
    acc[1][0]=MFMA(A1,B0,acc[1][0]); acc[1][1]=MFMA(A1,B1,acc[1][1]);        \
    acc[1][2]=MFMA(A1,B2,acc[1][2]); acc[1][3]=MFMA(A1,B3,acc[1][3]);        \
    acc[2][0]=MFMA(A2,B0,acc[2][0]); acc[2][1]=MFMA(A2,B1,acc[2][1]);        \
    acc[2][2]=MFMA(A2,B2,acc[2][2]); acc[2][3]=MFMA(A2,B3,acc[2][3]);        \
    acc[3][0]=MFMA(A3,B0,acc[3][0]); acc[3][1]=MFMA(A3,B1,acc[3][1]);        \
    acc[3][2]=MFMA(A3,B2,acc[3][2]); acc[3][3]=MFMA(A3,B3,acc[3][3]);        \
    __builtin_amdgcn_s_setprio(0);

  STAGE(0, 0);
  STAGE(1, 1);

  int cur = 0;
  for (int kt = 0; kt < NT; ++kt) {
    if (kt + 1 < NT) { asm volatile("s_waitcnt vmcnt(8)" ::: "memory"); }
    else             { asm volatile("s_waitcnt vmcnt(0)" ::: "memory"); }
    SCHB; SBAR;
    const short* Ad = As[cur];
    const short* Bd = Bs[cur];
    short8 a00, a01, a02, a03, b00, b01, b02, b03;
    short8 a10, a11, a12, a13, b10, b11, b12, b13;
    a00 = LD8(Ad, abase + 0 * 1024 + s0);
    a01 = LD8(Ad, abase + 1 * 1024 + s0);
    a02 = LD8(Ad, abase + 2 * 1024 + s0);
    a03 = LD8(Ad, abase + 3 * 1024 + s0);
    b00 = LD8(Bd, bbase + 0 * 1024 + s0);
    b01 = LD8(Bd, bbase + 1 * 1024 + s0);
    b02 = LD8(Bd, bbase + 2 * 1024 + s0);
    b03 = LD8(Bd, bbase + 3 * 1024 + s0);
    a10 = LD8(Ad, abase + 0 * 1024 + s1);
    a11 = LD8(Ad, abase + 1 * 1024 + s1);
    a12 = LD8(Ad, abase + 2 * 1024 + s1);
    a13 = LD8(Ad, abase + 3 * 1024 + s1);
    b10 = LD8(Bd, bbase + 0 * 1024 + s1);
    b11 = LD8(Bd, bbase + 1 * 1024 + s1);
    b12 = LD8(Bd, bbase + 2 * 1024 + s1);
    b13 = LD8(Bd, bbase + 3 * 1024 + s1);
    SCHB;
    asm volatile("s_waitcnt lgkmcnt(8)" ::: "memory");
    SCHB;
    MFMA16(a00, a01, a02, a03, b00, b01, b02, b03)
    SCHB;
    asm volatile("s_waitcnt lgkmcnt(0)" ::: "memory");
    SCHB; SBAR;
    if (kt + 2 < NT) STAGE(kt + 2, cur);
    SCHB;
    MFMA16(a10, a11, a12, a13, b10, b11, b12, b13)
    SCHB;
    cur ^= 1;
  }

#pragma unroll
  for (int mi = 0; mi < 4; ++mi) {
#pragma unroll
    for (int ni = 0; ni < 4; ++ni) {
#pragma unroll
      for (int j = 0; j < 4; ++j) {
        int r  = (int)row0 + wm * 64 + mi * 16 + lhi * 4 + j;
        int cc = (int)col0 + wc * 64 + ni * 16 + lr;
        float v = acc[mi][ni][j];
        size_t idx = (size_t)bz * 524288 + (size_t)r * 1024 + cc;
        float g = 1.f / (1.f + __expf(-v));
        Cout[idx] = X[idx] * g;
      }
    }
  }
#undef MFMA16
#undef STAGE
#undef GLL
#undef LD8
#undef MFMA
#undef SBAR
#undef SCHB
}

extern "C" void kernel_launch(void* const* d_in, const int* in_sizes, int n_in,
                              void* d_out, int out_size, void* d_ws, size_t ws_size,
                              hipStream_t stream) {
  const float* x    = (const float*)d_in[0];   // [32,512,1024]
  const float* w1   = (const float*)d_in[1];   // [1024,512]
  const float* w2   = (const float*)d_in[2];   // [512,1024]
  const float* ln_w = (const float*)d_in[3];   // [1024]
  const float* ln_b = (const float*)d_in[4];   // [1024]
  float* out = (float*)d_out;

  char* ws = (char*)d_ws;
  short* Deo    = (short*)(ws);                  //  1,048,576 B [2][512][512]
  short* w1_bf  = (short*)(ws + 1048576);        //  1,048,576 B
  short* w2_bf  = (short*)(ws + 2097152);        //  1,048,576 B
  short* freqT  = (short*)(ws + 3145728);        // 33,554,432 B [b][k][c]
  short* z1t    = (short*)(ws + 36700160);       // 67,108,864 B [b][p][o]
  short* eo     = z1t;                           // e/o alias z1t (dead by GEMM2)
  float2* part  = (float2*)(ws + 103809024);     //    524,288 B [4][16384]
  float2* musd  = (float2*)(ws + 104857600);     //    131,072 B [16384]
  // total ~105 MB

  prep_eo<<<dim3(8192), dim3(256), 0, stream>>>(x, eo);
  cast_w<<<dim3(1024), dim3(256), 0, stream>>>(w1, w2, w1_bf, w2_bf);
  build_Deo<<<dim3(2048), dim3(256), 0, stream>>>(Deo);

  // GEMM1 (even/odd): C[k',(b,c)] = sum_n Deo[p][k',n]*eo[p][(b,c),n]
  // -> freqT rows 2k'+p, + LN partials. K=512, NT=16.
  gemm1F<<<dim3(512), dim3(256), 0, stream>>>(
      Deo, eo, (void*)freqT, part, 512, 16, 262144, 8388608);

  // LN stats: fold 4 partials -> (mu, rstd) per (b,c)
  ln_stats<<<dim3(64), dim3(256), 0, stream>>>(part, musd);

  // LN apply: normalize freqT in place (streaming, vectorized)
  ln_apply<<<dim3(8192), dim3(256), 0, stream>>>(freqT, musd, ln_w, ln_b);

  // GEMM2 (8-phase 256^2): C[p,o] = sum_c Ht[b][p,c]*w1[o,c], relu -> z1t
  gemm2p8<<<dim3(512), dim3(512), 0, stream>>>(
      freqT, w1_bf, z1t, 512, 8, 524288);

  // GEMM3: C[o2,p] = sum_j w2[o2,j]*z1t[b][p,j]; out = x * sigmoid(C)
  gemm3k<<<dim3(1024), dim3(256), 0, stream>>>(
      w2_bf, z1t, out, x, 1024, 16, 1048576);
}

// Round 20
// 155.239 us; speedup vs baseline: 1.0630x; 1.0098x over previous
//
#include <hip/hip_runtime.h>
#include <hip/hip_bf16.h>
#include <math.h>

typedef short short8 __attribute__((ext_vector_type(8)));
typedef short short4v __attribute__((ext_vector_type(4)));
typedef float f32x4 __attribute__((ext_vector_type(4)));

__device__ __forceinline__ short f2bf(float f) {
  union { float f; unsigned u; } v; v.f = f;
  unsigned r = v.u + 0x7FFFu + ((v.u >> 16) & 1u);
  return (short)(r >> 16);
}
__device__ __forceinline__ float bf2f(short s) {
  union { unsigned u; float f; } v; v.u = ((unsigned)(unsigned short)s) << 16;
  return v.f;
}

// -------- merged prologue: blocks 0-1023 cast w1|w2; 1024-3071 build Deo --
__global__ __launch_bounds__(256) void prep_wd(const float* __restrict__ w1,
                                               const float* __restrict__ w2,
                                               short* __restrict__ w1_bf,
                                               short* __restrict__ w2_bf,
                                               short* __restrict__ D) {
  int blk = blockIdx.x;
  if (blk < 1024) {
    int i = blk * 256 + threadIdx.x;             // 262144 (x4 elems)
    const float* src = (i < 131072) ? w1 : w2;
    short* dst = (i < 131072) ? w1_bf : w2_bf;
    int j = (i < 131072) ? i : i - 131072;
    float4 v = ((const float4*)src)[j];
    short4v o;
    o.x = f2bf(v.x); o.y = f2bf(v.y); o.z = f2bf(v.z); o.w = f2bf(v.w);
    ((short4v*)dst)[j] = o;
  } else {
    int t = (blk - 1024) * 256 + threadIdx.x;    // 2*512*512 = 524288
    int parity = t >> 18, rem = t & 262143;
    int k2 = rem >> 9, n = rem & 511;
    const float s = 1.5339807878856412e-03f;     // pi/2048
    float arg = (s * (float)(2 * k2 + parity)) * (float)(2 * n + 1);
    D[t] = f2bf(2.0f * cosf(arg));
  }
}

// -------- DCT even/odd prep: e[n]=x[n]+x[1023-n], o[n]=x[n]-x[1023-n] -----
__global__ __launch_bounds__(256) void prep_eo(const float* __restrict__ x,
                                               short* __restrict__ eo) {
  int t = blockIdx.x * 256 + threadIdx.x;     // 16384 * 128
  int bc = t >> 7, n0 = (t & 127) * 4;        // n0 in [0,512)
  const float* xr = x + (size_t)bc * 1024;
  float4 f = *(const float4*)(xr + n0);
  float4 r = *(const float4*)(xr + 1020 - n0);
  short4v ef, of;
  ef.x = f2bf(f.x + r.w); ef.y = f2bf(f.y + r.z); ef.z = f2bf(f.z + r.y); ef.w = f2bf(f.w + r.x);
  of.x = f2bf(f.x - r.w); of.y = f2bf(f.y - r.z); of.z = f2bf(f.z - r.y); of.w = f2bf(f.w - r.x);
  *(short4v*)&eo[(size_t)bc * 512 + n0] = ef;
  *(short4v*)&eo[8388608 + (size_t)bc * 512 + n0] = of;
}

// -------- fold 4 row-block partials -> per-(b,c) mu, rstd -----------------
__global__ __launch_bounds__(256) void ln_stats(const float2* __restrict__ partial,
                                                float2* __restrict__ musd) {
  int n = blockIdx.x * 256 + threadIdx.x;   // 16384
  float S = 0.f, Q = 0.f;
#pragma unroll
  for (int r = 0; r < 4; ++r) {
    float2 p = partial[(size_t)r * 16384 + n];
    S += p.x; Q += p.y;
  }
  float mu  = S * (1.f / 1024.f);
  float var = Q * (1.f / 1024.f) - mu * mu;   // biased, like nn.LayerNorm
  float2 o; o.x = mu; o.y = rsqrtf(var + 1e-6f);
  musd[n] = o;
}

// -------- streaming LN apply: freqT[b][k][c] in place, short8/thread ------
__global__ __launch_bounds__(256) void ln_apply(short* __restrict__ freqT,
                                                const float2* __restrict__ musd,
                                                const float* __restrict__ lnw,
                                                const float* __restrict__ lnb) {
  int t = blockIdx.x * 256 + threadIdx.x;
  int c8 = t & 63;
  int k  = (t >> 6) & 1023;
  int b  = t >> 16;
  size_t idx = ((size_t)b << 19) + (size_t)k * 512 + (size_t)c8 * 8;
  short8 v = *(const short8*)&freqT[idx];
  float w  = lnw[k];
  float bb = lnb[k];
  const float2* ms = &musd[b * 512 + c8 * 8];
  short8 o;
#pragma unroll
  for (int j = 0; j < 8; ++j) {
    float f = bf2f(v[j]);
    float2 m = ms[j];
    o[j] = f2bf((f - m.x) * m.y * w + bb);
  }
  *(short8*)&freqT[idx] = o;
}

// ======== 256x128 BK=32 dbuf BT-GEMM (r13 structure) — GEMM1 ==============
__global__ __launch_bounds__(256, 2) void gemm1F(
    const short* __restrict__ A, const short* __restrict__ B,
    void* __restrict__ Cout, float2* __restrict__ P,
    int K, int NT, long strideA, long strideB)
{
  __shared__ short As[2][8192];    // 256 rows x 32 k
  __shared__ short Bs[2][4096];    // 128 rows x 32 k
  const int tid = threadIdx.x;     // 256
  const int l   = tid & 63;
  const int w   = tid >> 6;        // wave 0..3
  const int wm  = w >> 1;
  const int wc  = w & 1;
  const int lr  = l & 15;
  const int lhi = l >> 4;

  const int nwg = gridDim.x, q = nwg >> 3, orig = blockIdx.x;
  const int wgid = (orig & 7) * q + (orig >> 3);
  int bx = wgid & 1, bz = (wgid >> 1) & 1, by = wgid >> 2;

  const long row0 = (long)bx * 256, col0 = (long)by * 128;
  const short* Ab = A + (size_t)bz * strideA + (size_t)row0 * K;
  const short* Bb = B + (size_t)bz * strideB + (size_t)col0 * K;

  const int sx    = (lhi ^ ((lr >> 1) & 3)) * 8;
  const int abase = (wm * 128 + lr) * 32;
  const int bbase = (wc * 64  + lr) * 32;

  f32x4 acc[8][4];
#pragma unroll
  for (int i = 0; i < 8; ++i)
#pragma unroll
    for (int j = 0; j < 4; ++j) acc[i][j] = (f32x4){0.f, 0.f, 0.f, 0.f};

#define GLL(SRC, DST) __builtin_amdgcn_global_load_lds(                      \
      (const __attribute__((address_space(1))) void*)(SRC),                  \
      (__attribute__((address_space(3))) void*)(DST), 16, 0, 0)

#define STAGE(KT, D) do {                                                    \
    const size_t kb_ = (size_t)(KT) * 32;                                    \
    _Pragma("unroll")                                                        \
    for (int r_ = 0; r_ < 4; ++r_) {                                         \
      int c_ = r_ * 256 + tid; int row_ = c_ >> 2; int sl_ = c_ & 3;         \
      int sc_ = (sl_ ^ ((row_ >> 1) & 3)) * 8;                               \
      GLL(Ab + (size_t)row_ * K + kb_ + sc_, &As[D][row_ * 32 + sl_ * 8]);   \
    }                                                                        \
    _Pragma("unroll")                                                        \
    for (int r_ = 0; r_ < 2; ++r_) {                                         \
      int c_ = r_ * 256 + tid; int row_ = c_ >> 2; int sl_ = c_ & 3;         \
      int sc_ = (sl_ ^ ((row_ >> 1) & 3)) * 8;                               \
      GLL(Bb + (size_t)row_ * K + kb_ + sc_, &Bs[D][row_ * 32 + sl_ * 8]);   \
    }                                                                        \
  } while (0)

#define LD8(PTR, OFF) (*(const short8*)&(PTR)[OFF])
#define MFMA(AV, BV, C) __builtin_amdgcn_mfma_f32_16x16x32_bf16(AV, BV, C, 0, 0, 0)
#define SBAR __builtin_amdgcn_s_barrier()
#define SCHB __builtin_amdgcn_sched_barrier(0)

#define MROW(MI, AV)                                                         \
    acc[MI][0] = MFMA(AV, b0, acc[MI][0]);                                   \
    acc[MI][1] = MFMA(AV, b1, acc[MI][1]);                                   \
    acc[MI][2] = MFMA(AV, b2, acc[MI][2]);                                   \
    acc[MI][3] = MFMA(AV, b3, acc[MI][3]);

  STAGE(0, 0);
  STAGE(1, 1);

  int cur = 0;
  for (int kt = 0; kt < NT; ++kt) {
    if (kt + 1 < NT) { asm volatile("s_waitcnt vmcnt(6)" ::: "memory"); }
    else             { asm volatile("s_waitcnt vmcnt(0)" ::: "memory"); }
    SCHB; SBAR;
    const short* Ad = As[cur];
    const short* Bd = Bs[cur];
    short8 a0, a1, a2, a3, a4, a5, a6, a7, b0, b1, b2, b3;
    a0 = LD8(Ad, abase + 0 * 512 + sx);
    a1 = LD8(Ad, abase + 1 * 512 + sx);
    b0 = LD8(Bd, bbase + 0 * 512 + sx);
    b1 = LD8(Bd, bbase + 1 * 512 + sx);
    b2 = LD8(Bd, bbase + 2 * 512 + sx);
    b3 = LD8(Bd, bbase + 3 * 512 + sx);
    a2 = LD8(Ad, abase + 2 * 512 + sx);
    a3 = LD8(Ad, abase + 3 * 512 + sx);
    a4 = LD8(Ad, abase + 4 * 512 + sx);
    a5 = LD8(Ad, abase + 5 * 512 + sx);
    a6 = LD8(Ad, abase + 6 * 512 + sx);
    a7 = LD8(Ad, abase + 7 * 512 + sx);
    SCHB;
    asm volatile("s_waitcnt lgkmcnt(6)" ::: "memory");
    SCHB;
    __builtin_amdgcn_s_setprio(1);
    MROW(0, a0) MROW(1, a1)
    __builtin_amdgcn_s_setprio(0);
    SCHB;
    asm volatile("s_waitcnt lgkmcnt(0)" ::: "memory");
    SCHB; SBAR;
    if (kt + 2 < NT) STAGE(kt + 2, cur);
    SCHB;
    __builtin_amdgcn_s_setprio(1);
    MROW(2, a2) MROW(3, a3) MROW(4, a4) MROW(5, a5) MROW(6, a6) MROW(7, a7)
    __builtin_amdgcn_s_setprio(0);
    SCHB;
    cur ^= 1;
  }

  float sv[4], qv[4];
#pragma unroll
  for (int ni = 0; ni < 4; ++ni) { sv[ni] = 0.f; qv[ni] = 0.f; }

#pragma unroll
  for (int mi = 0; mi < 8; ++mi) {
#pragma unroll
    for (int ni = 0; ni < 4; ++ni) {
#pragma unroll
      for (int j = 0; j < 4; ++j) {
        int r  = (int)row0 + wm * 128 + mi * 16 + lhi * 4 + j;
        int cc = (int)col0 + wc * 64 + ni * 16 + lr;
        float v = acc[mi][ni][j];
        sv[ni] += v; qv[ni] += v * v;
        int rr = r * 2 + bz;
        ((short*)Cout)[((size_t)(cc >> 9) << 19) + (size_t)rr * 512 + (cc & 511)] = f2bf(v);
      }
    }
  }

  {
    __syncthreads();
    float* redS = (float*)&As[0][0];
    float* redQ = redS + 1024;
    const int contrib = wm * 4 + lhi;
#pragma unroll
    for (int ni = 0; ni < 4; ++ni) {
      int ccl = wc * 64 + ni * 16 + lr;
      redS[ccl * 8 + contrib] = sv[ni];
      redQ[ccl * 8 + contrib] = qv[ni];
    }
    __syncthreads();
    if (tid < 128) {
      float S = 0.f, Q = 0.f;
#pragma unroll
      for (int i = 0; i < 8; ++i) { S += redS[tid * 8 + i]; Q += redQ[tid * 8 + i]; }
      float2 o; o.x = S; o.y = Q;
      P[(size_t)(bz * 2 + bx) * 16384 + col0 + tid] = o;
    }
  }
#undef MROW
#undef STAGE
}

// ======== 256x256 8-phase BT-GEMM (r8 structure, EPI1) — GEMM2 ============
__global__ __launch_bounds__(512, 2) void gemm2p8(
    const short* __restrict__ A, const short* __restrict__ B,
    short* __restrict__ Cout, int K, int NT, long strideA)
{
  __shared__ short As[2][16384];
  __shared__ short Bs[2][16384];
  const int tid = threadIdx.x;
  const int l   = tid & 63;
  const int w   = tid >> 6;        // wave 0..7
  const int wm  = w >> 2;          // 0..1
  const int wn  = w & 3;           // 0..3
  const int l7  = l & 7;
  const int lr  = l & 15;
  const int lhi = l >> 4;

  const int nwg = gridDim.x, q = nwg >> 3, orig = blockIdx.x;
  const int wgid = (orig & 7) * q + (orig >> 3);
  const int bx = wgid & 3, by = (wgid >> 2) & 3, bz = wgid >> 4;

  const long row0 = (long)bx * 256, col0 = (long)by * 256;
  const short* Ab = A + (size_t)bz * strideA + (size_t)row0 * K;
  const short* Bb = B + (size_t)col0 * K;

  const int rowb  = w * 8 + (l >> 3);
  const int colel = (l7 ^ (l >> 3)) * 8;
  const int abase = (wm * 16 + lr) * 64;
  const int bbase = (wn * 16 + lr) * 64;
  const int s0 = ((lhi    ) ^ l7) * 8;
  const int s1 = ((lhi + 4) ^ l7) * 8;

  f32x4 acc[8][4];
#pragma unroll
  for (int i = 0; i < 8; ++i)
#pragma unroll
    for (int j = 0; j < 4; ++j) acc[i][j] = (f32x4){0.f, 0.f, 0.f, 0.f};

#define ST_HALF(OPb, OPlds, T, H) do {                                       \
    const size_t ko_ = (size_t)(T) * 64 + colel;                             \
    const short* sb_ = (OPb) + (size_t)((H) * 128 + rowb) * K + ko_;         \
    short* db_ = &OPlds[(T) & 1][(H) * 8192 + w * 512 + l * 8];              \
    GLL(sb_, db_);                                                           \
    GLL(sb_ + (size_t)64 * K, db_ + 4096);                                   \
  } while (0)

#define QUAD16(MIH, A0, A1, A2, A3, B0, B1, B2, B3)                          \
    __builtin_amdgcn_s_setprio(1);                                           \
    acc[MIH+0][0]=MFMA(A0,B0,acc[MIH+0][0]); acc[MIH+0][1]=MFMA(A0,B1,acc[MIH+0][1]); \
    acc[MIH+0][2]=MFMA(A0,B2,acc[MIH+0][2]); acc[MIH+0][3]=MFMA(A0,B3,acc[MIH+0][3]); \
    acc[MIH+1][0]=MFMA(A1,B0,acc[MIH+1][0]); acc[MIH+1][1]=MFMA(A1,B1,acc[MIH+1][1]); \
    acc[MIH+1][2]=MFMA(A1,B2,acc[MIH+1][2]); acc[MIH+1][3]=MFMA(A1,B3,acc[MIH+1][3]); \
    acc[MIH+2][0]=MFMA(A2,B0,acc[MIH+2][0]); acc[MIH+2][1]=MFMA(A2,B1,acc[MIH+2][1]); \
    acc[MIH+2][2]=MFMA(A2,B2,acc[MIH+2][2]); acc[MIH+2][3]=MFMA(A2,B3,acc[MIH+2][3]); \
    acc[MIH+3][0]=MFMA(A3,B0,acc[MIH+3][0]); acc[MIH+3][1]=MFMA(A3,B1,acc[MIH+3][1]); \
    acc[MIH+3][2]=MFMA(A3,B2,acc[MIH+3][2]); acc[MIH+3][3]=MFMA(A3,B3,acc[MIH+3][3]); \
    __builtin_amdgcn_s_setprio(0);

#define LGKM0 asm volatile("s_waitcnt lgkmcnt(0)" ::: "memory")

  ST_HALF(Bb, Bs, 0, 0); ST_HALF(Bb, Bs, 0, 1);
  ST_HALF(Ab, As, 0, 0); ST_HALF(Ab, As, 0, 1);
  ST_HALF(Bb, Bs, 1, 0); ST_HALF(Bb, Bs, 1, 1);
  ST_HALF(Ab, As, 1, 0);
  asm volatile("s_waitcnt vmcnt(6)" ::: "memory");
  SBAR;

  short8 b00, b01, b10, b11, b20, b21, b30, b31;
  short8 a0, a1, a2, a3;
  int cur = 0;
  for (int kt = 0; kt < NT; ++kt) {
    const short* Ad = As[cur];
    const short* Bd = Bs[cur];

    a0 = LD8(Ad, 0 * 2048 + abase + s0);
    a1 = LD8(Ad, 1 * 2048 + abase + s0);
    a2 = LD8(Ad, 2 * 2048 + abase + s0);
    a3 = LD8(Ad, 3 * 2048 + abase + s0);
    b00 = LD8(Bd, bbase + s0);          b01 = LD8(Bd, bbase + s1);
    b10 = LD8(Bd, 4096 + bbase + s0);   b11 = LD8(Bd, 4096 + bbase + s1);
    b20 = LD8(Bd, 8192 + bbase + s0);
    b30 = LD8(Bd, 12288 + bbase + s0);
    if (kt + 1 < NT) ST_HALF(Ab, As, kt + 1, 1);
    SCHB; SBAR;
    LGKM0; SCHB;
    QUAD16(0, a0, a1, a2, a3, b00, b10, b20, b30)
    SCHB; SBAR;

    a0 = LD8(Ad, 8192 + 0 * 2048 + abase + s0);
    a1 = LD8(Ad, 8192 + 1 * 2048 + abase + s0);
    a2 = LD8(Ad, 8192 + 2 * 2048 + abase + s0);
    a3 = LD8(Ad, 8192 + 3 * 2048 + abase + s0);
    b21 = LD8(Bd, 8192 + bbase + s1);
    b31 = LD8(Bd, 12288 + bbase + s1);
    if (kt + 2 < NT) ST_HALF(Bb, Bs, kt + 2, 0);
    SCHB; SBAR;
    LGKM0; SCHB;
    QUAD16(4, a0, a1, a2, a3, b00, b10, b20, b30)
    SCHB; SBAR;

    a0 = LD8(Ad, 0 * 2048 + abase + s1);
    a1 = LD8(Ad, 1 * 2048 + abase + s1);
    a2 = LD8(Ad, 2 * 2048 + abase + s1);
    a3 = LD8(Ad, 3 * 2048 + abase + s1);
    if (kt + 2 < NT) ST_HALF(Bb, Bs, kt + 2, 1);
    SCHB; SBAR;
    LGKM0; SCHB;
    QUAD16(0, a0, a1, a2, a3, b01, b11, b21, b31)
    SCHB; SBAR;

    a0 = LD8(Ad, 8192 + 0 * 2048 + abase + s1);
    a1 = LD8(Ad, 8192 + 1 * 2048 + abase + s1);
    a2 = LD8(Ad, 8192 + 2 * 2048 + abase + s1);
    a3 = LD8(Ad, 8192 + 3 * 2048 + abase + s1);
    if (kt + 2 < NT) ST_HALF(Ab, As, kt + 2, 0);
    if (kt + 2 < NT)      { asm volatile("s_waitcnt vmcnt(6)" ::: "memory"); }
    else if (kt + 1 < NT) { asm volatile("s_waitcnt vmcnt(0)" ::: "memory"); }
    SCHB; SBAR;
    LGKM0; SCHB;
    QUAD16(4, a0, a1, a2, a3, b01, b11, b21, b31)
    SCHB; SBAR;

    cur ^= 1;
  }

#pragma unroll
  for (int mi = 0; mi < 8; ++mi) {
#pragma unroll
    for (int ni = 0; ni < 4; ++ni) {
#pragma unroll
      for (int j = 0; j < 4; ++j) {
        int r  = (int)row0 + (mi >> 2) * 128 + (mi & 3) * 32 + wm * 16 + lhi * 4 + j;
        int cc = (int)col0 + (ni >> 1) * 128 + (ni & 1) * 64 + wn * 16 + lr;
        float v = acc[mi][ni][j];
        Cout[(size_t)bz * 1048576 + (size_t)r * 1024 + cc] = f2bf(v > 0.f ? v : 0.f);
      }
    }
  }
#undef QUAD16
#undef ST_HALF
#undef LGKM0
}

// ======== 128x128 dbuf BT-GEMM, 4 waves, 2 blocks/CU (r9) — GEMM3 =========
__global__ __launch_bounds__(256, 2) void gemm3k(
    const short* __restrict__ A, const short* __restrict__ B,
    float* __restrict__ Cout, const float* __restrict__ X,
    int K, int NT, long strideB)
{
  __shared__ short As[2][8192];
  __shared__ short Bs[2][8192];
  const int tid = threadIdx.x;
  const int l   = tid & 63;
  const int w   = tid >> 6;
  const int wm  = w >> 1;
  const int wc  = w & 1;
  const int l7  = l & 7;
  const int lr  = l & 15;
  const int lhi = l >> 4;

  const int nwg = gridDim.x, q = nwg >> 3, orig = blockIdx.x;
  const int wgid = (orig & 7) * q + (orig >> 3);
  int bx = wgid & 3, by = (wgid >> 2) & 7, bz = wgid >> 5;

  const long row0 = (long)bx * 128, col0 = (long)by * 128;
  const short* Ab = A + (size_t)row0 * K;
  const short* Bb = B + (size_t)bz * strideB + (size_t)col0 * K;

  const int rowb  = tid >> 3;
  const int colel = ((tid & 7) ^ ((tid >> 3) & 7)) * 8;
  const int abase = (wm * 64 + lr) * 64;
  const int bbase = (wc * 64 + lr) * 64;
  const int s0 = ((lhi    ) ^ l7) * 8;
  const int s1 = ((lhi + 4) ^ l7) * 8;

  f32x4 acc[4][4];
#pragma unroll
  for (int i = 0; i < 4; ++i)
#pragma unroll
    for (int j = 0; j < 4; ++j) acc[i][j] = (f32x4){0.f, 0.f, 0.f, 0.f};

#define STAGE(KT, D) do {                                                    \
    const size_t ko_ = (size_t)(KT) * 64 + colel;                            \
    _Pragma("unroll")                                                        \
    for (int r_ = 0; r_ < 4; ++r_)                                           \
      GLL(Ab + (size_t)(r_ * 32 + rowb) * K + ko_,                           \
          &As[D][(r_ * 32 + rowb) * 64 + (tid & 7) * 8]);                    \
    _Pragma("unroll")                                                        \
    for (int r_ = 0; r_ < 4; ++r_)                                           \
      GLL(Bb + (size_t)(r_ * 32 + rowb) * K + ko_,                           \
          &Bs[D][(r_ * 32 + rowb) * 64 + (tid & 7) * 8]);                    \
  } while (0)

#define MFMA16(A0, A1, A2, A3, B0, B1, B2, B3)                               \
    __builtin_amdgcn_s_setprio(1);                                           \
    acc[0][0]=MFMA(A0,B0,acc[0][0]); acc[0][1]=MFMA(A0,B1,acc[0][1]);        \
    acc[0][2]=MFMA(A0,B2,acc[0][2]); acc[0][3]=MFMA(A0,B3,acc[0][3]);        \
    acc[1][0]=MFMA(A1,B0,acc[1][0]); acc[1][1]=MFMA(A1,B1,acc[1][1]);        \
    acc[1][2]=MFMA(A1,B2,acc[1][2]); acc[1][3]=MFMA(A1,B3,acc[1][3]);        \
    acc[2][0]=MFMA(A2,B0,acc[2][0]); acc[2][1]=MFMA(A2,B1,acc[2][1]);        \
    acc[2][2]=MFMA(A2,B2,acc[2][2]); acc[2][3]=MFMA(A2,B3,acc[2][3]);        \
    acc[3][0]=MFMA(A3,B0,acc[3][0]); acc[3][1]=MFMA(A3,B1,acc[3][1]);        \
    acc[3][2]=MFMA(A3,B2,acc[3][2]); acc[3][3]=MFMA(A3,B3,acc[3][3]);        \
    __builtin_amdgcn_s_setprio(0);

  STAGE(0, 0);
  STAGE(1, 1);

  int cur = 0;
  for (int kt = 0; kt < NT; ++kt) {
    if (kt + 1 < NT) { asm volatile("s_waitcnt vmcnt(8)" ::: "memory"); }
    else             { asm volatile("s_waitcnt vmcnt(0)" ::: "memory"); }
    SCHB; SBAR;
    const short* Ad = As[cur];
    const short* Bd = Bs[cur];
    short8 a00, a01, a02, a03, b00, b01, b02, b03;
    short8 a10, a11, a12, a13, b10, b11, b12, b13;
    a00 = LD8(Ad, abase + 0 * 1024 + s0);
    a01 = LD8(Ad, abase + 1 * 1024 + s0);
    a02 = LD8(Ad, abase + 2 * 1024 + s0);
    a03 = LD8(Ad, abase + 3 * 1024 + s0);
    b00 = LD8(Bd, bbase + 0 * 1024 + s0);
    b01 = LD8(Bd, bbase + 1 * 1024 + s0);
    b02 = LD8(Bd, bbase + 2 * 1024 + s0);
    b03 = LD8(Bd, bbase + 3 * 1024 + s0);
    a10 = LD8(Ad, abase + 0 * 1024 + s1);
    a11 = LD8(Ad, abase + 1 * 1024 + s1);
    a12 = LD8(Ad, abase + 2 * 1024 + s1);
    a13 = LD8(Ad, abase + 3 * 1024 + s1);
    b10 = LD8(Bd, bbase + 0 * 1024 + s1);
    b11 = LD8(Bd, bbase + 1 * 1024 + s1);
    b12 = LD8(Bd, bbase + 2 * 1024 + s1);
    b13 = LD8(Bd, bbase + 3 * 1024 + s1);
    SCHB;
    asm volatile("s_waitcnt lgkmcnt(8)" ::: "memory");
    SCHB;
    MFMA16(a00, a01, a02, a03, b00, b01, b02, b03)
    SCHB;
    asm volatile("s_waitcnt lgkmcnt(0)" ::: "memory");
    SCHB; SBAR;
    if (kt + 2 < NT) STAGE(kt + 2, cur);
    SCHB;
    MFMA16(a10, a11, a12, a13, b10, b11, b12, b13)
    SCHB;
    cur ^= 1;
  }

#pragma unroll
  for (int mi = 0; mi < 4; ++mi) {
#pragma unroll
    for (int ni = 0; ni < 4; ++ni) {
#pragma unroll
      for (int j = 0; j < 4; ++j) {
        int r  = (int)row0 + wm * 64 + mi * 16 + lhi * 4 + j;
        int cc = (int)col0 + wc * 64 + ni * 16 + lr;
        float v = acc[mi][ni][j];
        size_t idx = (size_t)bz * 524288 + (size_t)r * 1024 + cc;
        float g = 1.f / (1.f + __expf(-v));
        Cout[idx] = X[idx] * g;
      }
    }
  }
#undef MFMA16
#undef STAGE
#undef GLL
#undef LD8
#undef MFMA
#undef SBAR
#undef SCHB
}

extern "C" void kernel_launch(void* const* d_in, const int* in_sizes, int n_in,
                              void* d_out, int out_size, void* d_ws, size_t ws_size,
                              hipStream_t stream) {
  const float* x    = (const float*)d_in[0];   // [32,512,1024]
  const float* w1   = (const float*)d_in[1];   // [1024,512]
  const float* w2   = (const float*)d_in[2];   // [512,1024]
  const float* ln_w = (const float*)d_in[3];   // [1024]
  const float* ln_b = (const float*)d_in[4];   // [1024]
  float* out = (float*)d_out;

  char* ws = (char*)d_ws;
  short* Deo    = (short*)(ws);                  //  1,048,576 B [2][512][512]
  short* w1_bf  = (short*)(ws + 1048576);        //  1,048,576 B
  short* w2_bf  = (short*)(ws + 2097152);        //  1,048,576 B
  short* freqT  = (short*)(ws + 3145728);        // 33,554,432 B [b][k][c]
  short* z1t    = (short*)(ws + 36700160);       // 67,108,864 B [b][p][o]
  short* eo     = z1t;                           // e/o alias z1t (dead by GEMM2)
  float2* part  = (float2*)(ws + 103809024);     //    524,288 B [4][16384]
  float2* musd  = (float2*)(ws + 104857600);     //    131,072 B [16384]
  // total ~105 MB

  prep_eo<<<dim3(8192), dim3(256), 0, stream>>>(x, eo);
  prep_wd<<<dim3(3072), dim3(256), 0, stream>>>(w1, w2, w1_bf, w2_bf, Deo);

  // GEMM1 (even/odd): C[k',(b,c)] = sum_n Deo[p][k',n]*eo[p][(b,c),n]
  // -> freqT rows 2k'+p, + LN partials. K=512, NT=16.
  gemm1F<<<dim3(512), dim3(256), 0, stream>>>(
      Deo, eo, (void*)freqT, part, 512, 16, 262144, 8388608);

  // LN stats: fold 4 partials -> (mu, rstd) per (b,c)
  ln_stats<<<dim3(64), dim3(256), 0, stream>>>(part, musd);

  // LN apply: normalize freqT in place (streaming, vectorized)
  ln_apply<<<dim3(8192), dim3(256), 0, stream>>>(freqT, musd, ln_w, ln_b);

  // GEMM2 (8-phase 256^2): C[p,o] = sum_c Ht[b][p,c]*w1[o,c], relu -> z1t
  gemm2p8<<<dim3(512), dim3(512), 0, stream>>>(
      freqT, w1_bf, z1t, 512, 8, 524288);

  // GEMM3: C[o2,p] = sum_j w2[o2,j]*z1t[b][p,j]; out = x * sigmoid(C)
  gemm3k<<<dim3(1024), dim3(256), 0, stream>>>(
      w2_bf, z1t, out, x, 1024, 16, 1048576);
}